// Round 1
// baseline (690.736 us; speedup 1.0000x reference)
//
#include <hip/hip_runtime.h>

#define B_   2
#define S_   1024
#define H_   1024
#define NH_  8
#define HD_  128
#define E_   8
#define MI_  1024
#define SI_  2048
#define T_   2048
#define CAP_ 2048

typedef unsigned short u16;
typedef __attribute__((ext_vector_type(4))) float f32x4;
typedef __attribute__((ext_vector_type(4))) unsigned short u16x4;
typedef __attribute__((ext_vector_type(4))) unsigned int u32x4;
typedef __attribute__((ext_vector_type(8))) __bf16 bf16x8;

__device__ __forceinline__ u16 f2bf(float f) {
  unsigned int u = __builtin_bit_cast(unsigned int, f);
  u = (u + 0x7fffu + ((u >> 16) & 1u)) >> 16;
  return (u16)u;
}
__device__ __forceinline__ float bf2f(u16 u) {
  return __builtin_bit_cast(float, (unsigned int)u << 16);
}
__device__ __forceinline__ float wave_sum(float v) {
#pragma unroll
  for (int o = 32; o; o >>= 1) v += __shfl_down(v, o, 64);
  return v;
}
__device__ __forceinline__ float wave_max(float v) {
#pragma unroll
  for (int o = 32; o; o >>= 1) v = fmaxf(v, __shfl_down(v, o, 64));
  return v;
}

// ---------------- fp32 -> bf16 weight conversion (with optional expert-interleave expand)
// out[i + (i/chunk)*chunk + off] = bf16(in[i])
__global__ void cvt_expand(const float* __restrict__ in, u16* __restrict__ out,
                           long n, long chunk, long off) {
  long i = ((long)blockIdx.x * 256 + threadIdx.x) * 4;
  if (i >= n) return;
  f32x4 v = *(const f32x4*)(in + i);
  long o = i + (i / chunk) * chunk + off;
  u16x4 r;
#pragma unroll
  for (int c = 0; c < 4; c++) r[c] = f2bf(v[c]);
  *(u16x4*)(out + o) = r;
}

// ---------------- RMSNorm -> bf16 (also records 1/rms for exact fp32 gating)
__global__ void rmsnorm_cvt(const float* __restrict__ x, const float* __restrict__ w,
                            u16* __restrict__ out, float* __restrict__ rstd) {
  int t = blockIdx.x, tid = threadIdx.x;
  const float* xr = x + (long)t * H_;
  f32x4 v = ((const f32x4*)xr)[tid];
  float ss = v[0]*v[0] + v[1]*v[1] + v[2]*v[2] + v[3]*v[3];
  __shared__ float red[4];
  float s = wave_sum(ss);
  if ((tid & 63) == 0) red[tid >> 6] = s;
  __syncthreads();
  float tot = red[0] + red[1] + red[2] + red[3];
  float r = rsqrtf(tot * (1.0f / H_) + 1e-6f);
  if (tid == 0) rstd[t] = r;
  u16x4 o;
#pragma unroll
  for (int c = 0; c < 4; c++) o[c] = f2bf(v[c] * r * w[tid * 4 + c]);
  ((u16x4*)(out + (long)t * H_))[tid] = o;
}

// ---------------- RoPE + layout change (b,s,h,d)->(b,h,s,d), fp32->bf16
__global__ void rope_cvt(const float* __restrict__ q, const float* __restrict__ cs,
                         const float* __restrict__ sn, u16* __restrict__ qb) {
  int rid = blockIdx.x * 2 + (threadIdx.x >> 7);  // row over (b*S+s)*NH+h
  int d = threadIdx.x & 127;
  int h = rid & (NH_ - 1);
  int bs = rid >> 3;
  int s = bs & (S_ - 1);
  int b = bs >> 10;
  long base = (long)rid * HD_;
  float v = q[base + d];
  float o = (d < 64) ? (-q[base + d + 64]) : q[base + d - 64];
  float res = v * cs[s * HD_ + d] + o * sn[s * HD_ + d];
  long ob = ((long)((b * NH_ + h) * S_ + s)) * HD_ + d;
  qb[ob] = f2bf(res);
}

// ---------------- V transpose: (b,s,h,d) fp32 -> (b,h,d,s) bf16
__global__ void vtrans(const float* __restrict__ v, u16* __restrict__ vt) {
  int bh = blockIdx.z, b = bh >> 3, h = bh & 7;
  int s0 = blockIdx.x * 32, d0 = blockIdx.y * 32;
  __shared__ u16 tile[32][33];
  for (int i = threadIdx.y; i < 32; i += 8) {
    float val = v[(((long)(b * S_ + s0 + i)) * NH_ + h) * HD_ + d0 + threadIdx.x];
    tile[i][threadIdx.x] = f2bf(val);
  }
  __syncthreads();
  for (int i = threadIdx.y; i < 32; i += 8) {
    vt[((long)bh * HD_ + d0 + i) * S_ + s0 + threadIdx.x] = tile[threadIdx.x][i];
  }
}

// ---------------- causal softmax row kernel: scores fp32 -> P bf16
__global__ void softmax_causal(const float* __restrict__ scores, u16* __restrict__ P) {
  int q = blockIdx.x, h = blockIdx.y, tid = threadIdx.x;
  const float* s = scores + ((long)h * S_ + q) * S_;
  u16* p = P + ((long)h * S_ + q) * S_;
  int valid = q + 1;
  int base = tid * 4;
  const float scale = 0.08838834764831845f;  // 1/sqrt(128)
  f32x4 v = ((const f32x4*)s)[tid];
  float xv[4];
  float mx = -1e30f;
#pragma unroll
  for (int c = 0; c < 4; c++) {
    xv[c] = (base + c < valid) ? v[c] * scale : -1e30f;
    mx = fmaxf(mx, xv[c]);
  }
  __shared__ float redA[4], redB[4];
  float wm = wave_max(mx);
  if ((tid & 63) == 0) redA[tid >> 6] = wm;
  __syncthreads();
  float M = fmaxf(fmaxf(redA[0], redA[1]), fmaxf(redA[2], redA[3]));
  float ex[4];
  float sum = 0.f;
#pragma unroll
  for (int c = 0; c < 4; c++) {
    ex[c] = (base + c < valid) ? __expf(xv[c] - M) : 0.f;
    sum += ex[c];
  }
  float ws = wave_sum(sum);
  if ((tid & 63) == 0) redB[tid >> 6] = ws;
  __syncthreads();
  float Z = redB[0] + redB[1] + redB[2] + redB[3];
  float inv = 1.0f / Z;
  u16x4 o;
#pragma unroll
  for (int c = 0; c < 4; c++) o[c] = f2bf(ex[c] * inv);
  ((u16x4*)p)[tid] = o;
}

// ---------------- fp32 gate + top2 + grouping (one wave per token)
__global__ void gate_topk(const float* __restrict__ x1, const float* __restrict__ ln2w,
                          const float* __restrict__ rstd, const float* __restrict__ gw,
                          int* __restrict__ cursor, int* __restrict__ arow,
                          float* __restrict__ aw) {
  int t = blockIdx.x * 4 + (threadIdx.x >> 6);
  int lane = threadIdx.x & 63;
  const float* xr = x1 + (long)t * H_;
  float r = rstd[t];
  float acc[E_];
#pragma unroll
  for (int e = 0; e < E_; e++) acc[e] = 0.f;
  for (int j = 0; j < 16; j++) {
    int i = j * 64 + lane;
    float xv = xr[i] * r * ln2w[i];
#pragma unroll
    for (int e = 0; e < E_; e++) acc[e] += xv * gw[e * H_ + i];
  }
#pragma unroll
  for (int e = 0; e < E_; e++) acc[e] = wave_sum(acc[e]);
  if (lane == 0) {
    float mx = acc[0];
#pragma unroll
    for (int e = 1; e < E_; e++) mx = fmaxf(mx, acc[e]);
    float p[E_], z = 0.f;
#pragma unroll
    for (int e = 0; e < E_; e++) { p[e] = __expf(acc[e] - mx); z += p[e]; }
    int e0 = 0;
#pragma unroll
    for (int e = 1; e < E_; e++) if (p[e] > p[e0]) e0 = e;
    int e1 = (e0 == 0) ? 1 : 0;
#pragma unroll
    for (int e = 0; e < E_; e++) if (e != e0 && p[e] > p[e1]) e1 = e;
    float q0 = p[e0] / z, q1 = p[e1] / z;
    float invs = 1.0f / (q0 + q1 + 1e-20f);
    int pos0 = atomicAdd(cursor + e0, 1);
    int pos1 = atomicAdd(cursor + e1, 1);
    arow[t * 2] = e0 * CAP_ + pos0;
    arow[t * 2 + 1] = e1 * CAP_ + pos1;
    aw[t * 2] = q0 * invs;
    aw[t * 2 + 1] = q1 * invs;
  }
}

// ---------------- gather token rows into per-expert slabs
__global__ void gather_rows(const u16* __restrict__ xn, const int* __restrict__ arow,
                            u16* __restrict__ xg) {
  int a = blockIdx.x;
  int t = a >> 1;
  int row = arow[a];
  u16x4 v = ((const u16x4*)(xn + (long)t * H_))[threadIdx.x];
  ((u16x4*)(xg + (long)row * H_))[threadIdx.x] = v;
}

// ---------------- silu(g)*u over concat-gu rows
__global__ void silu_mul(const u16* __restrict__ gu, u16* __restrict__ h, int half) {
  long row = blockIdx.y;
  int i = blockIdx.x * 1024 + threadIdx.x * 4;
  const u16* g = gu + row * 2 * half + i;
  const u16* u = gu + row * 2 * half + half + i;
  u16x4 gv = *(const u16x4*)g, uv = *(const u16x4*)u;
  u16x4 o;
#pragma unroll
  for (int c = 0; c < 4; c++) {
    float x = bf2f(gv[c]);
    float s = x / (1.f + __expf(-x));
    o[c] = f2bf(s * bf2f(uv[c]));
  }
  *(u16x4*)(h + row * half + i) = o;
}

// ---------------- final: out = x1 + shared + w0*y[r0] + w1*y[r1]
__global__ void final_combine(const float* __restrict__ x1, const float* __restrict__ ys,
                              const u16* __restrict__ y, const int* __restrict__ arow,
                              const float* __restrict__ aw, float* __restrict__ out) {
  int t = blockIdx.x;
  int i = threadIdx.x * 4;
  int r0 = arow[t * 2], r1 = arow[t * 2 + 1];
  float w0 = aw[t * 2], w1 = aw[t * 2 + 1];
  f32x4 a = *(const f32x4*)(x1 + (long)t * H_ + i);
  f32x4 b = *(const f32x4*)(ys + (long)t * H_ + i);
  u16x4 y0 = *(const u16x4*)(y + (long)r0 * H_ + i);
  u16x4 y1 = *(const u16x4*)(y + (long)r1 * H_ + i);
  f32x4 o;
#pragma unroll
  for (int c = 0; c < 4; c++)
    o[c] = a[c] + b[c] + w0 * bf2f(y0[c]) + w1 * bf2f(y1[c]);
  *(f32x4*)(out + (long)t * H_ + i) = o;
}

// ---------------- bf16 MFMA GEMM: C = A (MxK, k-contig) * B^T (B stored NxK, k-contig)
// 128x128 tile, BK=32, 4 waves, wave tile 64x64 as 4x4 frags of 16x16x32.
// LDS rows padded to 40 elems (80B) -> conflict-free ds_read_b128.
#define LDK 40
template <int STORE_BF16, int ADD_RES, int CAUSAL_SKIP, int K_CAUSAL>
__global__ __launch_bounds__(256) void gemm_bt(
    const u16* __restrict__ Ag, const u16* __restrict__ Bg, void* __restrict__ Cg,
    const float* __restrict__ Res, int K, int lda, int ldb, int ldc,
    long sAz, long sBz, long sCz, const int* __restrict__ mlimit) {
  int z = blockIdx.z;
  int m0 = blockIdx.y * 128, n0 = blockIdx.x * 128;
  if (mlimit && m0 >= mlimit[z]) return;
  if (CAUSAL_SKIP && n0 > m0 + 127) return;
  int kend = K_CAUSAL ? min(K, m0 + 128) : K;
  const u16* A = Ag + z * sAz;
  const u16* B = Bg + z * sBz;

  __shared__ __align__(16) u16 As[128 * LDK];
  __shared__ __align__(16) u16 Bs[128 * LDK];
  int tid = threadIdx.x;
  int lane = tid & 63, wave = tid >> 6;
  int wm = (wave & 1) * 64, wn = (wave >> 1) * 64;
  int srow = tid >> 2, skc = tid & 3;
  int la = lane & 15, qd = lane >> 4;

  f32x4 acc[4][4];
#pragma unroll
  for (int i = 0; i < 4; i++)
#pragma unroll
    for (int j = 0; j < 4; j++) acc[i][j] = (f32x4){0.f, 0.f, 0.f, 0.f};

  for (int k0 = 0; k0 < kend; k0 += 32) {
    __syncthreads();
    u32x4 a0 = *(const u32x4*)(A + (long)(m0 + srow) * lda + k0 + skc * 8);
    u32x4 a1 = *(const u32x4*)(A + (long)(m0 + srow + 64) * lda + k0 + skc * 8);
    u32x4 b0 = *(const u32x4*)(B + (long)(n0 + srow) * ldb + k0 + skc * 8);
    u32x4 b1 = *(const u32x4*)(B + (long)(n0 + srow + 64) * ldb + k0 + skc * 8);
    *(u32x4*)(As + srow * LDK + skc * 8) = a0;
    *(u32x4*)(As + (srow + 64) * LDK + skc * 8) = a1;
    *(u32x4*)(Bs + srow * LDK + skc * 8) = b0;
    *(u32x4*)(Bs + (srow + 64) * LDK + skc * 8) = b1;
    __syncthreads();
    bf16x8 af[4], bff[4];
#pragma unroll
    for (int i = 0; i < 4; i++)
      af[i] = *(const bf16x8*)(As + (wm + i * 16 + la) * LDK + qd * 8);
#pragma unroll
    for (int j = 0; j < 4; j++)
      bff[j] = *(const bf16x8*)(Bs + (wn + j * 16 + la) * LDK + qd * 8);
#pragma unroll
    for (int i = 0; i < 4; i++)
#pragma unroll
      for (int j = 0; j < 4; j++)
        acc[i][j] = __builtin_amdgcn_mfma_f32_16x16x32_bf16(af[i], bff[j], acc[i][j], 0, 0, 0);
  }

#pragma unroll
  for (int i = 0; i < 4; i++) {
#pragma unroll
    for (int j = 0; j < 4; j++) {
      int col = n0 + wn + j * 16 + la;
#pragma unroll
      for (int r = 0; r < 4; r++) {
        int row = m0 + wm + i * 16 + qd * 4 + r;
        float v = acc[i][j][r];
        long ci = (long)z * sCz + (long)row * ldc + col;
        if (ADD_RES) v += Res[(long)row * ldc + col];
        if (STORE_BF16) ((u16*)Cg)[ci] = f2bf(v);
        else ((float*)Cg)[ci] = v;
      }
    }
  }
}

extern "C" void kernel_launch(void* const* d_in, const int* in_sizes, int n_in,
                              void* d_out, int out_size, void* d_ws, size_t ws_size,
                              hipStream_t stream) {
  const float* hidden = (const float*)d_in[0];
  const float* ln1w = (const float*)d_in[1];
  const float* ln2w = (const float*)d_in[2];
  const float* q_w = (const float*)d_in[3];
  const float* k_w = (const float*)d_in[4];
  const float* v_w = (const float*)d_in[5];
  const float* o_w = (const float*)d_in[6];
  const float* cosp = (const float*)d_in[7];
  const float* sinp = (const float*)d_in[8];
  const float* gate_w = (const float*)d_in[9];
  const float* eg_w = (const float*)d_in[10];
  const float* eu_w = (const float*)d_in[11];
  const float* ed_w = (const float*)d_in[12];
  const float* sg_w = (const float*)d_in[13];
  const float* su_w = (const float*)d_in[14];
  const float* sd_w = (const float*)d_in[15];
  float* out = (float*)d_out;

  char* w = (char*)d_ws;
  const size_t MB = 1u << 20;
  u16* qwb = (u16*)(w + 0 * MB);
  u16* kwb = (u16*)(w + 2 * MB);
  u16* vwb = (u16*)(w + 4 * MB);
  u16* owb = (u16*)(w + 6 * MB);
  u16* egu = (u16*)(w + 8 * MB);    // (E, 2*MI, H) g rows then u rows per expert
  u16* edb = (u16*)(w + 40 * MB);   // (E, H, MI)
  u16* sgu = (u16*)(w + 56 * MB);   // (2*SI, H)
  u16* sdb = (u16*)(w + 64 * MB);   // (H, SI)
  float* x1 = (float*)(w + 68 * MB);
  u16* xn = (u16*)(w + 76 * MB);
  u16* attn = (u16*)(w + 80 * MB);
  int* cursor = (int*)(w + 84 * MB);
  int* arow = (int*)(w + 84 * MB + 1024);
  float* aw = (float*)(w + 84 * MB + 20 * 1024);
  float* rstd = (float*)(w + 84 * MB + 40 * 1024);
  // phase-1 arena
  float* qf = (float*)(w + 85 * MB);
  float* kf = (float*)(w + 93 * MB);
  float* vf = (float*)(w + 101 * MB);
  u16* qb = (u16*)(w + 109 * MB);
  u16* kb = (u16*)(w + 113 * MB);
  u16* vt = (u16*)(w + 117 * MB);
  float* scores = (float*)(w + 121 * MB);  // (NH,S,S) per batch, 32MB
  u16* P = (u16*)(w + 153 * MB);           // 16MB
  // phase-2 arena (aliases phase-1)
  u16* xg = (u16*)(w + 85 * MB);    // (E,CAP,H) 32MB
  u16* gu = (u16*)(w + 117 * MB);   // (E,CAP,2MI) 64MB
  u16* hbuf = (u16*)(w + 181 * MB); // (E,CAP,MI) 32MB
  u16* y = (u16*)(w + 117 * MB);    // (E,CAP,H) 32MB (gu dead by then)
  u16* gus = (u16*)(w + 149 * MB);  // (T,2*SI) 16MB
  u16* hs = (u16*)(w + 165 * MB);   // (T,SI) 8MB
  float* ys = (float*)(w + 173 * MB);  // (T,H) 8MB

  const long M1 = 1048576, M2 = 2097152, M8 = 8388608;

  // ---- weight conversions fp32->bf16
  cvt_expand<<<1024, 256, 0, stream>>>(q_w, qwb, M1, M1, 0);
  cvt_expand<<<1024, 256, 0, stream>>>(k_w, kwb, M1, M1, 0);
  cvt_expand<<<1024, 256, 0, stream>>>(v_w, vwb, M1, M1, 0);
  cvt_expand<<<1024, 256, 0, stream>>>(o_w, owb, M1, M1, 0);
  cvt_expand<<<8192, 256, 0, stream>>>(eg_w, egu, M8, (long)MI_ * H_, 0);
  cvt_expand<<<8192, 256, 0, stream>>>(eu_w, egu, M8, (long)MI_ * H_, (long)MI_ * H_);
  cvt_expand<<<8192, 256, 0, stream>>>(ed_w, edb, M8, M8, 0);
  cvt_expand<<<2048, 256, 0, stream>>>(sg_w, sgu, M2, M2, 0);
  cvt_expand<<<2048, 256, 0, stream>>>(su_w, sgu, M2, M2, M2);
  cvt_expand<<<2048, 256, 0, stream>>>(sd_w, sdb, M2, M2, 0);

  // ---- attention
  rmsnorm_cvt<<<T_, 256, 0, stream>>>(hidden, ln1w, xn, rstd);
  gemm_bt<0, 0, 0, 0><<<dim3(8, 16, 1), 256, 0, stream>>>(xn, qwb, qf, nullptr, 1024, 1024, 1024, 1024, 0, 0, 0, nullptr);
  gemm_bt<0, 0, 0, 0><<<dim3(8, 16, 1), 256, 0, stream>>>(xn, kwb, kf, nullptr, 1024, 1024, 1024, 1024, 0, 0, 0, nullptr);
  gemm_bt<0, 0, 0, 0><<<dim3(8, 16, 1), 256, 0, stream>>>(xn, vwb, vf, nullptr, 1024, 1024, 1024, 1024, 0, 0, 0, nullptr);
  rope_cvt<<<8192, 256, 0, stream>>>(qf, cosp, sinp, qb);
  rope_cvt<<<8192, 256, 0, stream>>>(kf, cosp, sinp, kb);
  vtrans<<<dim3(32, 4, 16), dim3(32, 8), 0, stream>>>(vf, vt);

  for (int b = 0; b < B_; b++) {
    gemm_bt<0, 0, 1, 0><<<dim3(8, 8, 8), 256, 0, stream>>>(
        qb + (long)b * NH_ * S_ * HD_, kb + (long)b * NH_ * S_ * HD_, scores, nullptr,
        128, 128, 128, 1024, (long)S_ * HD_, (long)S_ * HD_, (long)S_ * S_, nullptr);
    softmax_causal<<<dim3(1024, 8), 256, 0, stream>>>(scores, P);
    gemm_bt<1, 0, 0, 1><<<dim3(1, 8, 8), 256, 0, stream>>>(
        P, vt + (long)b * NH_ * HD_ * S_, attn + (long)b * S_ * H_, nullptr,
        1024, 1024, 1024, 1024, (long)S_ * S_, (long)HD_ * S_, (long)HD_, nullptr);
  }
  gemm_bt<0, 1, 0, 0><<<dim3(8, 16, 1), 256, 0, stream>>>(attn, owb, x1, hidden, 1024, 1024, 1024, 1024, 0, 0, 0, nullptr);

  // ---- MoE
  rmsnorm_cvt<<<T_, 256, 0, stream>>>(x1, ln2w, xn, rstd);
  hipMemsetAsync(cursor, 0, 64, stream);
  gate_topk<<<512, 256, 0, stream>>>(x1, ln2w, rstd, gate_w, cursor, arow, aw);
  gather_rows<<<4096, 256, 0, stream>>>(xn, arow, xg);
  gemm_bt<1, 0, 0, 0><<<dim3(16, 16, 8), 256, 0, stream>>>(
      xg, egu, gu, nullptr, 1024, 1024, 1024, 2 * MI_,
      (long)CAP_ * H_, (long)2 * MI_ * H_, (long)CAP_ * 2 * MI_, cursor);
  silu_mul<<<dim3(1, E_ * CAP_), 256, 0, stream>>>(gu, hbuf, MI_);
  gemm_bt<1, 0, 0, 0><<<dim3(8, 16, 8), 256, 0, stream>>>(
      hbuf, edb, y, nullptr, 1024, 1024, 1024, 1024,
      (long)CAP_ * MI_, (long)H_ * MI_, (long)CAP_ * H_, cursor);
  // shared MLP
  gemm_bt<1, 0, 0, 0><<<dim3(32, 16, 1), 256, 0, stream>>>(
      xn, sgu, gus, nullptr, 1024, 1024, 1024, 2 * SI_, 0, 0, 0, nullptr);
  silu_mul<<<dim3(2, T_), 256, 0, stream>>>(gus, hs, SI_);
  gemm_bt<0, 0, 0, 0><<<dim3(8, 16, 1), 256, 0, stream>>>(
      hs, sdb, ys, nullptr, 2048, 2048, 2048, 1024, 0, 0, 0, nullptr);

  final_combine<<<T_, 256, 0, stream>>>(x1, ys, y, arow, aw, out);
}

// Round 2
// 582.074 us; speedup vs baseline: 1.1867x; 1.1867x over previous
//
#include <hip/hip_runtime.h>

#define B_   2
#define S_   1024
#define H_   1024
#define NH_  8
#define HD_  128
#define E_   8
#define MI_  1024
#define SI_  2048
#define T_   2048
#define CAP_ 2048

typedef unsigned short u16;
typedef __attribute__((ext_vector_type(4))) float f32x4;
typedef __attribute__((ext_vector_type(4))) unsigned short u16x4;
typedef __attribute__((ext_vector_type(8))) __bf16 bf16x8;

__device__ __forceinline__ u16 f2bf(float f) {
  unsigned int u = __builtin_bit_cast(unsigned int, f);
  u = (u + 0x7fffu + ((u >> 16) & 1u)) >> 16;
  return (u16)u;
}
__device__ __forceinline__ float bf2f(u16 u) {
  return __builtin_bit_cast(float, (unsigned int)u << 16);
}
__device__ __forceinline__ float wave_sum(float v) {
#pragma unroll
  for (int o = 32; o; o >>= 1) v += __shfl_down(v, o, 64);
  return v;
}
__device__ __forceinline__ float wave_max(float v) {
#pragma unroll
  for (int o = 32; o; o >>= 1) v = fmaxf(v, __shfl_down(v, o, 64));
  return v;
}
// async global->LDS, 16B per lane, dest = ldsbase + lane*16
__device__ __forceinline__ void gll16(const u16* g, u16* l) {
  __builtin_amdgcn_global_load_lds((const __attribute__((address_space(1))) void*)g,
                                   (__attribute__((address_space(3))) void*)l, 16, 0, 0);
}

// ---------------- qkv+o weight convert: 4 x 1M fp32 -> contiguous bf16
__global__ void cvt4(const float* __restrict__ p0, const float* __restrict__ p1,
                     const float* __restrict__ p2, const float* __restrict__ p3,
                     u16* __restrict__ out) {
  int seg = blockIdx.x >> 10;
  long idx = ((long)(blockIdx.x & 1023) * 256 + threadIdx.x) * 4;
  const float* in = (seg == 0) ? p0 : (seg == 1) ? p1 : (seg == 2) ? p2 : p3;
  f32x4 v = *(const f32x4*)(in + idx);
  u16x4 r;
#pragma unroll
  for (int c = 0; c < 4; c++) r[c] = f2bf(v[c]);
  *(u16x4*)(out + (long)seg * 1048576 + idx) = r;
}

// ---------------- plain fp32->bf16
__global__ void cvt_plain(const float* __restrict__ in, u16* __restrict__ out, long n) {
  long i = ((long)blockIdx.x * 256 + threadIdx.x) * 4;
  if (i >= n) return;
  f32x4 v = *(const f32x4*)(in + i);
  u16x4 r;
#pragma unroll
  for (int c = 0; c < 4; c++) r[c] = f2bf(v[c]);
  *(u16x4*)(out + i) = r;
}

// ---------------- g/u 16-row interleave convert: out (nE, 2*rows, H)
// g row i -> out_row (i/16)*32 + i%16 ; u row i -> +16
__global__ void cvt_ilv(const float* __restrict__ g_in, const float* __restrict__ u_in,
                        u16* __restrict__ out, long rows, long nE) {
  long f = ((long)blockIdx.x * 256 + threadIdx.x) * 4;
  long per = rows * H_;
  if (f >= nE * per) return;
  const float* in = blockIdx.z ? u_in : g_in;
  long e = f / per;
  long rem = f - e * per;
  long i = rem >> 10;
  long hh = rem & 1023;
  long orow = (i >> 4) * 32 + (i & 15) + (blockIdx.z ? 16 : 0);
  f32x4 v = *(const f32x4*)(in + f);
  u16x4 r;
#pragma unroll
  for (int c = 0; c < 4; c++) r[c] = f2bf(v[c]);
  *(u16x4*)(out + (e * 2 * rows + orow) * H_ + hh) = r;
}

// ---------------- RMSNorm -> bf16
__global__ void rmsnorm_cvt(const float* __restrict__ x, const float* __restrict__ w,
                            u16* __restrict__ out) {
  int t = blockIdx.x, tid = threadIdx.x;
  f32x4 v = ((const f32x4*)(x + (long)t * H_))[tid];
  float ss = v[0]*v[0] + v[1]*v[1] + v[2]*v[2] + v[3]*v[3];
  __shared__ float red[4];
  float s = wave_sum(ss);
  if ((tid & 63) == 0) red[tid >> 6] = s;
  __syncthreads();
  float r = rsqrtf((red[0] + red[1] + red[2] + red[3]) * (1.0f / H_) + 1e-6f);
  f32x4 wv = ((const f32x4*)w)[tid];
  u16x4 o;
#pragma unroll
  for (int c = 0; c < 4; c++) o[c] = f2bf(v[c] * r * wv[c]);
  ((u16x4*)(out + (long)t * H_))[tid] = o;
}

// ---------------- fused RMSNorm2 + gate + top2 routing (one block per token)
__global__ void rmsnorm2_gate(const float* __restrict__ x1, const float* __restrict__ ln2w,
                              const float* __restrict__ gw, u16* __restrict__ xn,
                              int* __restrict__ cursor, int* __restrict__ arow,
                              float* __restrict__ aw) {
  int t = blockIdx.x, tid = threadIdx.x;
  int lane = tid & 63, wave = tid >> 6;
  f32x4 v = ((const f32x4*)(x1 + (long)t * H_))[tid];
  float ss = v[0]*v[0] + v[1]*v[1] + v[2]*v[2] + v[3]*v[3];
  __shared__ float redS[4];
  __shared__ float redE[4][E_];
  float s = wave_sum(ss);
  if (lane == 0) redS[wave] = s;
  __syncthreads();
  float r = rsqrtf((redS[0] + redS[1] + redS[2] + redS[3]) * (1.0f / H_) + 1e-6f);
  f32x4 wv = ((const f32x4*)ln2w)[tid];
  float xv[4];
  u16x4 o;
#pragma unroll
  for (int c = 0; c < 4; c++) { xv[c] = v[c] * r * wv[c]; o[c] = f2bf(xv[c]); }
  ((u16x4*)(xn + (long)t * H_))[tid] = o;
  float acc[E_];
#pragma unroll
  for (int e = 0; e < E_; e++) {
    f32x4 g = ((const f32x4*)(gw + (long)e * H_))[tid];
    acc[e] = xv[0]*g[0] + xv[1]*g[1] + xv[2]*g[2] + xv[3]*g[3];
  }
#pragma unroll
  for (int e = 0; e < E_; e++) acc[e] = wave_sum(acc[e]);
  if (lane == 0)
#pragma unroll
    for (int e = 0; e < E_; e++) redE[wave][e] = acc[e];
  __syncthreads();
  if (tid == 0) {
    float l[E_];
#pragma unroll
    for (int e = 0; e < E_; e++) l[e] = redE[0][e] + redE[1][e] + redE[2][e] + redE[3][e];
    float mx = l[0];
#pragma unroll
    for (int e = 1; e < E_; e++) mx = fmaxf(mx, l[e]);
    float p[E_], z = 0.f;
#pragma unroll
    for (int e = 0; e < E_; e++) { p[e] = __expf(l[e] - mx); z += p[e]; }
    int e0 = 0;
#pragma unroll
    for (int e = 1; e < E_; e++) if (p[e] > p[e0]) e0 = e;
    int e1 = (e0 == 0) ? 1 : 0;
#pragma unroll
    for (int e = 0; e < E_; e++) if (e != e0 && p[e] > p[e1]) e1 = e;
    float q0 = p[e0] / z, q1 = p[e1] / z;
    float invs = 1.0f / (q0 + q1 + 1e-20f);
    int pos0 = atomicAdd(cursor + e0, 1);
    int pos1 = atomicAdd(cursor + e1, 1);
    arow[t * 2] = e0 * CAP_ + pos0;
    arow[t * 2 + 1] = e1 * CAP_ + pos1;
    aw[t * 2] = q0 * invs;
    aw[t * 2 + 1] = q1 * invs;
  }
}

// ---------------- RoPE + layout change (b,s,h,d)->(b,h,s,d), fp32->bf16; z picks q/k
__global__ void rope_cvt(const float* __restrict__ qf, const float* __restrict__ cs,
                         const float* __restrict__ sn, u16* __restrict__ qbb) {
  const float* q = qf + (long)blockIdx.z * 2097152;
  u16* qb = qbb + (long)blockIdx.z * 2097152;
  int rid = blockIdx.x * 2 + (threadIdx.x >> 7);
  int d = threadIdx.x & 127;
  int h = rid & (NH_ - 1);
  int bs = rid >> 3;
  int s = bs & (S_ - 1);
  int b = bs >> 10;
  long base = (long)rid * HD_;
  float v = q[base + d];
  float o = (d < 64) ? (-q[base + d + 64]) : q[base + d - 64];
  float res = v * cs[s * HD_ + d] + o * sn[s * HD_ + d];
  qb[((long)((b * NH_ + h) * S_ + s)) * HD_ + d] = f2bf(res);
}

// ---------------- V transpose: (b,s,h,d) fp32 -> (b,h,d,s) bf16
__global__ void vtrans(const float* __restrict__ v, u16* __restrict__ vt) {
  int bh = blockIdx.z, b = bh >> 3, h = bh & 7;
  int s0 = blockIdx.x * 32, d0 = blockIdx.y * 32;
  __shared__ u16 tile[32][33];
  for (int i = threadIdx.y; i < 32; i += 8) {
    float val = v[(((long)(b * S_ + s0 + i)) * NH_ + h) * HD_ + d0 + threadIdx.x];
    tile[i][threadIdx.x] = f2bf(val);
  }
  __syncthreads();
  for (int i = threadIdx.y; i < 32; i += 8) {
    vt[((long)bh * HD_ + d0 + i) * S_ + s0 + threadIdx.x] = tile[threadIdx.x][i];
  }
}

// ---------------- causal softmax row: scores fp32 -> P bf16
__global__ void softmax_causal(const float* __restrict__ scores, u16* __restrict__ P) {
  int q = blockIdx.x, h = blockIdx.y, tid = threadIdx.x;
  const float* s = scores + ((long)h * S_ + q) * S_;
  u16* p = P + ((long)h * S_ + q) * S_;
  int valid = q + 1;
  int base = tid * 4;
  const float scale = 0.08838834764831845f;
  f32x4 v = ((const f32x4*)s)[tid];
  float xv[4];
  float mx = -1e30f;
#pragma unroll
  for (int c = 0; c < 4; c++) {
    xv[c] = (base + c < valid) ? v[c] * scale : -1e30f;
    mx = fmaxf(mx, xv[c]);
  }
  __shared__ float redA[4], redB[4];
  float wm = wave_max(mx);
  if ((tid & 63) == 0) redA[tid >> 6] = wm;
  __syncthreads();
  float M = fmaxf(fmaxf(redA[0], redA[1]), fmaxf(redA[2], redA[3]));
  float ex[4];
  float sum = 0.f;
#pragma unroll
  for (int c = 0; c < 4; c++) {
    ex[c] = (base + c < valid) ? __expf(xv[c] - M) : 0.f;
    sum += ex[c];
  }
  float ws = wave_sum(sum);
  if ((tid & 63) == 0) redB[tid >> 6] = ws;
  __syncthreads();
  float inv = 1.0f / (redB[0] + redB[1] + redB[2] + redB[3]);
  u16x4 o;
#pragma unroll
  for (int c = 0; c < 4; c++) o[c] = f2bf(ex[c] * inv);
  ((u16x4*)p)[tid] = o;
}

// ---------------- gather token rows into per-expert slabs
__global__ void gather_rows(const u16* __restrict__ xn, const int* __restrict__ arow,
                            u16* __restrict__ xg) {
  int a = blockIdx.x;
  int t = a >> 1;
  int row = arow[a];
  u16x4 v = ((const u16x4*)(xn + (long)t * H_))[threadIdx.x];
  ((u16x4*)(xg + (long)row * H_))[threadIdx.x] = v;
}

// ---------------- final: out = x1 + shared + w0*y[r0] + w1*y[r1]
__global__ void final_combine(const float* __restrict__ x1, const float* __restrict__ ys,
                              const u16* __restrict__ y, const int* __restrict__ arow,
                              const float* __restrict__ aw, float* __restrict__ out) {
  int t = blockIdx.x;
  int i = threadIdx.x * 4;
  int r0 = arow[t * 2], r1 = arow[t * 2 + 1];
  float w0 = aw[t * 2], w1 = aw[t * 2 + 1];
  f32x4 a = *(const f32x4*)(x1 + (long)t * H_ + i);
  f32x4 b = *(const f32x4*)(ys + (long)t * H_ + i);
  u16x4 y0 = *(const u16x4*)(y + (long)r0 * H_ + i);
  u16x4 y1 = *(const u16x4*)(y + (long)r1 * H_ + i);
  f32x4 o;
#pragma unroll
  for (int c = 0; c < 4; c++)
    o[c] = a[c] + b[c] + w0 * bf2f(y0[c]) + w1 * bf2f(y1[c]);
  *(f32x4*)(out + (long)t * H_ + i) = o;
}

// ---------------- bf16 MFMA GEMM, m97 structure: global_load_lds width-16 staging.
// C = A (MxK, k-contig) * B^T (B stored NxK, k-contig). 128x128 tile, BK=32,
// LDS unpadded rows of 32 elems (required by global_load_lds lane layout).
// FUSE_SILU: B's N-dim is 16-row interleaved g/u blocks; writes silu(g)*u as bf16
// to Cg with ldc = half-N row stride.
template <int STORE_BF16, int ADD_RES, int CAUSAL_SKIP, int K_CAUSAL, int FUSE_SILU>
__global__ __launch_bounds__(256) void gemm_bt(
    const u16* __restrict__ Ag, const u16* __restrict__ Bg, void* __restrict__ Cg,
    const float* __restrict__ Res, int K, int lda, int ldb, int ldc,
    long sAz, long sBz, long sCz, const int* __restrict__ mlimit) {
  int z = blockIdx.z;
  int m0 = blockIdx.y * 128, n0 = blockIdx.x * 128;
  if (mlimit && m0 >= mlimit[z]) return;
  if (CAUSAL_SKIP && n0 > m0 + 127) return;
  int kend = K_CAUSAL ? min(K, m0 + 128) : K;
  const u16* A = Ag + z * sAz;
  const u16* B = Bg + z * sBz;

  __shared__ __align__(16) u16 As[128 * 32];
  __shared__ __align__(16) u16 Bs[128 * 32];
  int tid = threadIdx.x;
  int lane = tid & 63, wave = tid >> 6;
  int wm = (wave & 1) * 64, wn = (wave >> 1) * 64;
  int la = lane & 15, qd = lane >> 4;
  int r0 = wave * 16 + (lane >> 2);  // staging row within 64-row half
  int c0 = (lane & 3) * 8;           // staging col chunk (8 elems = 16B)

  const u16* ap0 = A + (long)(m0 + r0) * lda + c0;
  const u16* ap1 = A + (long)(m0 + 64 + r0) * lda + c0;
  const u16* bp0 = B + (long)(n0 + r0) * ldb + c0;
  const u16* bp1 = B + (long)(n0 + 64 + r0) * ldb + c0;
  u16* as0 = As + wave * 512;
  u16* as1 = As + 2048 + wave * 512;
  u16* bs0 = Bs + wave * 512;
  u16* bs1 = Bs + 2048 + wave * 512;

  f32x4 acc[4][4];
#pragma unroll
  for (int i = 0; i < 4; i++)
#pragma unroll
    for (int j = 0; j < 4; j++) acc[i][j] = (f32x4){0.f, 0.f, 0.f, 0.f};

  for (int k0 = 0; k0 < kend; k0 += 32) {
    __syncthreads();
    gll16(ap0 + k0, as0);
    gll16(ap1 + k0, as1);
    gll16(bp0 + k0, bs0);
    gll16(bp1 + k0, bs1);
    __syncthreads();
    bf16x8 af[4], bf[4];
#pragma unroll
    for (int i = 0; i < 4; i++)
      af[i] = *(const bf16x8*)(As + (wm + i * 16 + la) * 32 + qd * 8);
#pragma unroll
    for (int j = 0; j < 4; j++)
      bf[j] = *(const bf16x8*)(Bs + (wn + j * 16 + la) * 32 + qd * 8);
#pragma unroll
    for (int i = 0; i < 4; i++)
#pragma unroll
      for (int j = 0; j < 4; j++)
        acc[i][j] = __builtin_amdgcn_mfma_f32_16x16x32_bf16(af[i], bf[j], acc[i][j], 0, 0, 0);
  }

  if (FUSE_SILU) {
#pragma unroll
    for (int i = 0; i < 4; i++) {
#pragma unroll
      for (int jp = 0; jp < 2; jp++) {
        int hcol = ((n0 + wn) >> 1) + (jp << 4) + la;
#pragma unroll
        for (int r = 0; r < 4; r++) {
          int row = m0 + wm + i * 16 + qd * 4 + r;
          float g = acc[i][jp * 2][r], u = acc[i][jp * 2 + 1][r];
          float sg = g / (1.f + __expf(-g));
          ((u16*)Cg)[(long)z * sCz + (long)row * ldc + hcol] = f2bf(sg * u);
        }
      }
    }
  } else {
#pragma unroll
    for (int i = 0; i < 4; i++) {
#pragma unroll
      for (int j = 0; j < 4; j++) {
        int col = n0 + wn + j * 16 + la;
#pragma unroll
        for (int r = 0; r < 4; r++) {
          int row = m0 + wm + i * 16 + qd * 4 + r;
          float v = acc[i][j][r];
          long ci = (long)z * sCz + (long)row * ldc + col;
          if (ADD_RES) v += Res[(long)row * ldc + col];
          if (STORE_BF16) ((u16*)Cg)[ci] = f2bf(v);
          else ((float*)Cg)[ci] = v;
        }
      }
    }
  }
}

extern "C" void kernel_launch(void* const* d_in, const int* in_sizes, int n_in,
                              void* d_out, int out_size, void* d_ws, size_t ws_size,
                              hipStream_t stream) {
  const float* hidden = (const float*)d_in[0];
  const float* ln1w = (const float*)d_in[1];
  const float* ln2w = (const float*)d_in[2];
  const float* q_w = (const float*)d_in[3];
  const float* k_w = (const float*)d_in[4];
  const float* v_w = (const float*)d_in[5];
  const float* o_w = (const float*)d_in[6];
  const float* cosp = (const float*)d_in[7];
  const float* sinp = (const float*)d_in[8];
  const float* gate_w = (const float*)d_in[9];
  const float* eg_w = (const float*)d_in[10];
  const float* eu_w = (const float*)d_in[11];
  const float* ed_w = (const float*)d_in[12];
  const float* sg_w = (const float*)d_in[13];
  const float* su_w = (const float*)d_in[14];
  const float* sd_w = (const float*)d_in[15];
  float* out = (float*)d_out;

  char* w = (char*)d_ws;
  const size_t MB = 1u << 20;
  u16* qwb = (u16*)(w + 0 * MB);     // q,k,v,o contiguous: 8MB
  u16* egu = (u16*)(w + 8 * MB);     // (E, 2*MI, H) 16-row interleaved g/u, 32MB
  u16* edb = (u16*)(w + 40 * MB);    // (E, H, MI) 16MB
  u16* sgu = (u16*)(w + 56 * MB);    // (2*SI, H) interleaved, 8MB
  u16* sdb = (u16*)(w + 64 * MB);    // (H, SI) 4MB
  float* x1 = (float*)(w + 68 * MB);
  u16* xn = (u16*)(w + 76 * MB);
  u16* attn = (u16*)(w + 80 * MB);
  int* cursor = (int*)(w + 84 * MB);
  int* arow = (int*)(w + 84 * MB + 1024);
  float* aw = (float*)(w + 84 * MB + 20 * 1024);
  // phase-1 arena
  float* qf = (float*)(w + 85 * MB);
  float* kf = (float*)(w + 93 * MB);
  float* vf = (float*)(w + 101 * MB);
  u16* qb = (u16*)(w + 109 * MB);
  u16* kb = (u16*)(w + 113 * MB);
  u16* vt = (u16*)(w + 117 * MB);
  float* scores = (float*)(w + 121 * MB);  // (NH,S,S) per batch, 32MB
  u16* P = (u16*)(w + 153 * MB);           // 16MB
  // phase-2 arena (aliases phase-1)
  u16* xg = (u16*)(w + 85 * MB);     // (E,CAP,H) 32MB
  u16* hbuf = (u16*)(w + 117 * MB);  // (E,CAP,MI) 32MB
  u16* y = (u16*)(w + 149 * MB);     // (E,CAP,H) 32MB
  u16* hs = (u16*)(w + 181 * MB);    // (T,SI) 8MB
  float* ys = (float*)(w + 189 * MB);  // (T,H) 8MB

  const long M1 = 1048576, M2 = 2097152, M8 = 8388608;

  // ---- weight conversions
  cvt4<<<4096, 256, 0, stream>>>(q_w, k_w, v_w, o_w, qwb);
  cvt_ilv<<<dim3(8192, 1, 2), 256, 0, stream>>>(eg_w, eu_w, egu, MI_, E_);
  cvt_plain<<<8192, 256, 0, stream>>>(ed_w, edb, M8);
  cvt_ilv<<<dim3(2048, 1, 2), 256, 0, stream>>>(sg_w, su_w, sgu, SI_, 1);
  cvt_plain<<<2048, 256, 0, stream>>>(sd_w, sdb, M2);

  // ---- attention
  rmsnorm_cvt<<<T_, 256, 0, stream>>>(hidden, ln1w, xn);
  gemm_bt<0, 0, 0, 0, 0><<<dim3(8, 16, 3), 256, 0, stream>>>(
      xn, qwb, qf, nullptr, 1024, 1024, 1024, 1024, 0, M1, M2, nullptr);
  rope_cvt<<<dim3(8192, 1, 2), 256, 0, stream>>>(qf, cosp, sinp, qb);
  vtrans<<<dim3(32, 4, 16), dim3(32, 8), 0, stream>>>(vf, vt);

  for (int b = 0; b < B_; b++) {
    gemm_bt<0, 0, 1, 0, 0><<<dim3(8, 8, 8), 256, 0, stream>>>(
        qb + (long)b * NH_ * S_ * HD_, kb + (long)b * NH_ * S_ * HD_, scores, nullptr,
        128, 128, 128, 1024, (long)S_ * HD_, (long)S_ * HD_, (long)S_ * S_, nullptr);
    softmax_causal<<<dim3(1024, 8), 256, 0, stream>>>(scores, P);
    gemm_bt<1, 0, 0, 1, 0><<<dim3(1, 8, 8), 256, 0, stream>>>(
        P, vt + (long)b * NH_ * HD_ * S_, attn + (long)b * S_ * H_, nullptr,
        1024, 1024, 1024, 1024, (long)S_ * S_, (long)HD_ * S_, (long)HD_, nullptr);
  }
  gemm_bt<0, 1, 0, 0, 0><<<dim3(8, 16, 1), 256, 0, stream>>>(
      attn, qwb + 3 * M1, x1, hidden, 1024, 1024, 1024, 1024, 0, 0, 0, nullptr);

  // ---- MoE
  hipMemsetAsync(cursor, 0, 64, stream);
  rmsnorm2_gate<<<T_, 256, 0, stream>>>(x1, ln2w, gate_w, xn, cursor, arow, aw);
  gather_rows<<<4096, 256, 0, stream>>>(xn, arow, xg);
  gemm_bt<1, 0, 0, 0, 1><<<dim3(16, 16, 8), 256, 0, stream>>>(
      xg, egu, hbuf, nullptr, 1024, 1024, 1024, MI_,
      (long)CAP_ * H_, (long)2 * MI_ * H_, (long)CAP_ * MI_, cursor);
  gemm_bt<1, 0, 0, 0, 0><<<dim3(8, 16, 8), 256, 0, stream>>>(
      hbuf, edb, y, nullptr, 1024, 1024, 1024, 1024,
      (long)CAP_ * MI_, (long)H_ * MI_, (long)CAP_ * H_, cursor);
  // shared MLP
  gemm_bt<1, 0, 0, 0, 1><<<dim3(32, 16, 1), 256, 0, stream>>>(
      xn, sgu, hs, nullptr, 1024, 1024, 1024, SI_, 0, 0, 0, nullptr);
  gemm_bt<0, 0, 0, 0, 0><<<dim3(8, 16, 1), 256, 0, stream>>>(
      hs, sdb, ys, nullptr, 2048, 2048, 2048, 1024, 0, 0, 0, nullptr);

  final_combine<<<T_, 256, 0, stream>>>(x1, ys, y, arow, aw, out);
}

// Round 4
// 517.678 us; speedup vs baseline: 1.3343x; 1.1244x over previous
//
#include <hip/hip_runtime.h>

#define B_   2
#define S_   1024
#define H_   1024
#define NH_  8
#define HD_  128
#define E_   8
#define MI_  1024
#define SI_  2048
#define T_   2048
#define CAP_ 2048

typedef unsigned short u16;
typedef __attribute__((ext_vector_type(4))) float f32x4;
typedef __attribute__((ext_vector_type(4))) unsigned short u16x4;
typedef __attribute__((ext_vector_type(8))) __bf16 bf16x8;

__device__ __forceinline__ u16 f2bf(float f) {
  unsigned int u = __builtin_bit_cast(unsigned int, f);
  u = (u + 0x7fffu + ((u >> 16) & 1u)) >> 16;
  return (u16)u;
}
__device__ __forceinline__ float bf2f(u16 u) {
  return __builtin_bit_cast(float, (unsigned int)u << 16);
}
__device__ __forceinline__ float wave_sum(float v) {
#pragma unroll
  for (int o = 32; o; o >>= 1) v += __shfl_down(v, o, 64);
  return v;
}
__device__ __forceinline__ float wave_max(float v) {
#pragma unroll
  for (int o = 32; o; o >>= 1) v = fmaxf(v, __shfl_down(v, o, 64));
  return v;
}
// async global->LDS, 16B per lane, dest = ldsbase + lane*16
__device__ __forceinline__ void gll16(const u16* g, u16* l) {
  __builtin_amdgcn_global_load_lds((const __attribute__((address_space(1))) void*)g,
                                   (__attribute__((address_space(3))) void*)l, 16, 0, 0);
}

// ---------------- qkv+o weight convert: 4 x 1M fp32 -> contiguous bf16
__global__ void cvt4(const float* __restrict__ p0, const float* __restrict__ p1,
                     const float* __restrict__ p2, const float* __restrict__ p3,
                     u16* __restrict__ out) {
  int seg = blockIdx.x >> 10;
  long idx = ((long)(blockIdx.x & 1023) * 256 + threadIdx.x) * 4;
  const float* in = (seg == 0) ? p0 : (seg == 1) ? p1 : (seg == 2) ? p2 : p3;
  f32x4 v = *(const f32x4*)(in + idx);
  u16x4 r;
#pragma unroll
  for (int c = 0; c < 4; c++) r[c] = f2bf(v[c]);
  *(u16x4*)(out + (long)seg * 1048576 + idx) = r;
}

// ---------------- plain fp32->bf16
__global__ void cvt_plain(const float* __restrict__ in, u16* __restrict__ out, long n) {
  long i = ((long)blockIdx.x * 256 + threadIdx.x) * 4;
  if (i >= n) return;
  f32x4 v = *(const f32x4*)(in + i);
  u16x4 r;
#pragma unroll
  for (int c = 0; c < 4; c++) r[c] = f2bf(v[c]);
  *(u16x4*)(out + i) = r;
}

// ---------------- g/u 16-row interleave convert: out (nE, 2*rows, H)
__global__ void cvt_ilv(const float* __restrict__ g_in, const float* __restrict__ u_in,
                        u16* __restrict__ out, long rows, long nE) {
  long f = ((long)blockIdx.x * 256 + threadIdx.x) * 4;
  long per = rows * H_;
  if (f >= nE * per) return;
  const float* in = blockIdx.z ? u_in : g_in;
  long e = f / per;
  long rem = f - e * per;
  long i = rem >> 10;
  long hh = rem & 1023;
  long orow = (i >> 4) * 32 + (i & 15) + (blockIdx.z ? 16 : 0);
  f32x4 v = *(const f32x4*)(in + f);
  u16x4 r;
#pragma unroll
  for (int c = 0; c < 4; c++) r[c] = f2bf(v[c]);
  *(u16x4*)(out + (e * 2 * rows + orow) * H_ + hh) = r;
}

// ---------------- RMSNorm -> bf16
__global__ void rmsnorm_cvt(const float* __restrict__ x, const float* __restrict__ w,
                            u16* __restrict__ out) {
  int t = blockIdx.x, tid = threadIdx.x;
  f32x4 v = ((const f32x4*)(x + (long)t * H_))[tid];
  float ss = v[0]*v[0] + v[1]*v[1] + v[2]*v[2] + v[3]*v[3];
  __shared__ float red[4];
  float s = wave_sum(ss);
  if ((tid & 63) == 0) red[tid >> 6] = s;
  __syncthreads();
  float r = rsqrtf((red[0] + red[1] + red[2] + red[3]) * (1.0f / H_) + 1e-6f);
  f32x4 wv = ((const f32x4*)w)[tid];
  u16x4 o;
#pragma unroll
  for (int c = 0; c < 4; c++) o[c] = f2bf(v[c] * r * wv[c]);
  ((u16x4*)(out + (long)t * H_))[tid] = o;
}

// ---------------- fused RMSNorm2 + gate + top2 (NO atomics; writes eidx + weights)
__global__ void rmsnorm2_gate(const float* __restrict__ x1, const float* __restrict__ ln2w,
                              const float* __restrict__ gw, u16* __restrict__ xn,
                              int* __restrict__ eidx, float* __restrict__ aw) {
  int t = blockIdx.x, tid = threadIdx.x;
  int lane = tid & 63, wave = tid >> 6;
  f32x4 v = ((const f32x4*)(x1 + (long)t * H_))[tid];
  float ss = v[0]*v[0] + v[1]*v[1] + v[2]*v[2] + v[3]*v[3];
  __shared__ float redS[4];
  __shared__ float redE[4][E_];
  float s = wave_sum(ss);
  if (lane == 0) redS[wave] = s;
  __syncthreads();
  float r = rsqrtf((redS[0] + redS[1] + redS[2] + redS[3]) * (1.0f / H_) + 1e-6f);
  f32x4 wv = ((const f32x4*)ln2w)[tid];
  float xv[4];
  u16x4 o;
#pragma unroll
  for (int c = 0; c < 4; c++) { xv[c] = v[c] * r * wv[c]; o[c] = f2bf(xv[c]); }
  ((u16x4*)(xn + (long)t * H_))[tid] = o;
  float acc[E_];
#pragma unroll
  for (int e = 0; e < E_; e++) {
    f32x4 g = ((const f32x4*)(gw + (long)e * H_))[tid];
    acc[e] = xv[0]*g[0] + xv[1]*g[1] + xv[2]*g[2] + xv[3]*g[3];
  }
#pragma unroll
  for (int e = 0; e < E_; e++) acc[e] = wave_sum(acc[e]);
  if (lane == 0)
#pragma unroll
    for (int e = 0; e < E_; e++) redE[wave][e] = acc[e];
  __syncthreads();
  if (tid == 0) {
    float l[E_];
#pragma unroll
    for (int e = 0; e < E_; e++) l[e] = redE[0][e] + redE[1][e] + redE[2][e] + redE[3][e];
    float mx = l[0];
#pragma unroll
    for (int e = 1; e < E_; e++) mx = fmaxf(mx, l[e]);
    float p[E_], z = 0.f;
#pragma unroll
    for (int e = 0; e < E_; e++) { p[e] = __expf(l[e] - mx); z += p[e]; }
    int e0 = 0;
#pragma unroll
    for (int e = 1; e < E_; e++) if (p[e] > p[e0]) e0 = e;
    int e1 = (e0 == 0) ? 1 : 0;
#pragma unroll
    for (int e = 0; e < E_; e++) if (e != e0 && p[e] > p[e1]) e1 = e;
    float q0 = p[e0] / z, q1 = p[e1] / z;
    float invs = 1.0f / (q0 + q1 + 1e-20f);
    eidx[t * 2] = e0;
    eidx[t * 2 + 1] = e1;
    aw[t * 2] = q0 * invs;
    aw[t * 2 + 1] = q1 * invs;
  }
}

// ---------------- single-workgroup routing scan: positions without global atomics
__global__ __launch_bounds__(256) void route_scan(const int* __restrict__ eidx,
                                                  int* __restrict__ arow,
                                                  int* __restrict__ cursor) {
  __shared__ int sc[E_][256];
  int tid = threadIdx.x;
  unsigned c0 = 0, c1 = 0;
  int ebuf[16];
#pragma unroll
  for (int i = 0; i < 16; i++) {
    int e = eidx[tid * 16 + i];
    ebuf[i] = e;
    if (e < 4) c0 += 1u << (8 * e); else c1 += 1u << (8 * (e - 4));
  }
#pragma unroll
  for (int e = 0; e < E_; e++)
    sc[e][tid] = (e < 4) ? (int)((c0 >> (8 * e)) & 0xff) : (int)((c1 >> (8 * (e - 4))) & 0xff);
  __syncthreads();
  for (int st = 1; st < 256; st <<= 1) {
    int v[E_];
#pragma unroll
    for (int e = 0; e < E_; e++) v[e] = (tid >= st) ? sc[e][tid - st] : 0;
    __syncthreads();
#pragma unroll
    for (int e = 0; e < E_; e++) sc[e][tid] += v[e];
    __syncthreads();
  }
  if (tid == 255)
#pragma unroll
    for (int e = 0; e < E_; e++) cursor[e] = sc[e][255];
  // convert inclusive -> exclusive base
  int base[E_];
#pragma unroll
  for (int e = 0; e < E_; e++) {
    int own = (e < 4) ? (int)((c0 >> (8 * e)) & 0xff) : (int)((c1 >> (8 * (e - 4))) & 0xff);
    base[e] = sc[e][tid] - own;
  }
  __syncthreads();
#pragma unroll
  for (int e = 0; e < E_; e++) sc[e][tid] = base[e];
  __syncthreads();
  unsigned r0 = 0, r1 = 0;
#pragma unroll
  for (int i = 0; i < 16; i++) {
    int e = ebuf[i];
    int run = (e < 4) ? (int)((r0 >> (8 * e)) & 0xff) : (int)((r1 >> (8 * (e - 4))) & 0xff);
    arow[tid * 16 + i] = e * CAP_ + sc[e][tid] + run;
    if (e < 4) r0 += 1u << (8 * e); else r1 += 1u << (8 * (e - 4));
  }
}

// ---------------- RoPE + layout change (b,s,h,d)->(b,h,s,d), fp32->bf16; z picks q/k
__global__ void rope_cvt(const float* __restrict__ qf, const float* __restrict__ cs,
                         const float* __restrict__ sn, u16* __restrict__ qbb) {
  const float* q = qf + (long)blockIdx.z * 2097152;
  u16* qb = qbb + (long)blockIdx.z * 2097152;
  int rid = blockIdx.x * 2 + (threadIdx.x >> 7);
  int d = threadIdx.x & 127;
  int h = rid & (NH_ - 1);
  int bs = rid >> 3;
  int s = bs & (S_ - 1);
  int b = bs >> 10;
  long base = (long)rid * HD_;
  float v = q[base + d];
  float o = (d < 64) ? (-q[base + d + 64]) : q[base + d - 64];
  float res = v * cs[s * HD_ + d] + o * sn[s * HD_ + d];
  qb[((long)((b * NH_ + h) * S_ + s)) * HD_ + d] = f2bf(res);
}

// ---------------- V transpose: (b,s,h,d) fp32 -> (b,h,d,s) bf16
__global__ void vtrans(const float* __restrict__ v, u16* __restrict__ vt) {
  int bh = blockIdx.z, b = bh >> 3, h = bh & 7;
  int s0 = blockIdx.x * 32, d0 = blockIdx.y * 32;
  __shared__ u16 tile[32][33];
  for (int i = threadIdx.y; i < 32; i += 8) {
    float val = v[(((long)(b * S_ + s0 + i)) * NH_ + h) * HD_ + d0 + threadIdx.x];
    tile[i][threadIdx.x] = f2bf(val);
  }
  __syncthreads();
  for (int i = threadIdx.y; i < 32; i += 8) {
    vt[((long)bh * HD_ + d0 + i) * S_ + s0 + threadIdx.x] = tile[threadIdx.x][i];
  }
}

// ---------------- causal softmax row: scores fp32 -> P bf16 (y = b*8+h, 16 total)
__global__ void softmax_causal(const float* __restrict__ scores, u16* __restrict__ P) {
  int q = blockIdx.x, bh = blockIdx.y, tid = threadIdx.x;
  const float* s = scores + ((long)bh * S_ + q) * S_;
  u16* p = P + ((long)bh * S_ + q) * S_;
  int valid = q + 1;
  int base = tid * 4;
  const float scale = 0.08838834764831845f;
  f32x4 v = ((const f32x4*)s)[tid];
  float xv[4];
  float mx = -1e30f;
#pragma unroll
  for (int c = 0; c < 4; c++) {
    xv[c] = (base + c < valid) ? v[c] * scale : -1e30f;
    mx = fmaxf(mx, xv[c]);
  }
  __shared__ float redA[4], redB[4];
  float wm = wave_max(mx);
  if ((tid & 63) == 0) redA[tid >> 6] = wm;
  __syncthreads();
  float M = fmaxf(fmaxf(redA[0], redA[1]), fmaxf(redA[2], redA[3]));
  float ex[4];
  float sum = 0.f;
#pragma unroll
  for (int c = 0; c < 4; c++) {
    ex[c] = (base + c < valid) ? __expf(xv[c] - M) : 0.f;
    sum += ex[c];
  }
  float ws = wave_sum(sum);
  if ((tid & 63) == 0) redB[tid >> 6] = ws;
  __syncthreads();
  float inv = 1.0f / (redB[0] + redB[1] + redB[2] + redB[3]);
  u16x4 o;
#pragma unroll
  for (int c = 0; c < 4; c++) o[c] = f2bf(ex[c] * inv);
  ((u16x4*)p)[tid] = o;
}

// ---------------- gather token rows into per-expert slabs
__global__ void gather_rows(const u16* __restrict__ xn, const int* __restrict__ arow,
                            u16* __restrict__ xg) {
  int a = blockIdx.x;
  int t = a >> 1;
  int row = arow[a];
  u16x4 v = ((const u16x4*)(xn + (long)t * H_))[threadIdx.x];
  ((u16x4*)(xg + (long)row * H_))[threadIdx.x] = v;
}

// ---------------- final: out = x1 + shared + w0*y[r0] + w1*y[r1]
__global__ void final_combine(const float* __restrict__ x1, const float* __restrict__ ys,
                              const u16* __restrict__ y, const int* __restrict__ arow,
                              const float* __restrict__ aw, float* __restrict__ out) {
  int t = blockIdx.x;
  int i = threadIdx.x * 4;
  int r0 = arow[t * 2], r1 = arow[t * 2 + 1];
  float w0 = aw[t * 2], w1 = aw[t * 2 + 1];
  f32x4 a = *(const f32x4*)(x1 + (long)t * H_ + i);
  f32x4 b = *(const f32x4*)(ys + (long)t * H_ + i);
  u16x4 y0 = *(const u16x4*)(y + (long)r0 * H_ + i);
  u16x4 y1 = *(const u16x4*)(y + (long)r1 * H_ + i);
  f32x4 o;
#pragma unroll
  for (int c = 0; c < 4; c++)
    o[c] = a[c] + b[c] + w0 * bf2f(y0[c]) + w1 * bf2f(y1[c]);
  *(f32x4*)(out + (long)t * H_ + i) = o;
}

// ---------------- bf16 MFMA GEMM, m97 structure (global_load_lds width-16).
// C = A (MxK, k-contig) * B^T (NxK, k-contig). 128x128 tile, BK=32, unpadded LDS.
// CSPLIT: C z-offset = (z>>3)*(S*H) + (z&7)*sCz   [attention (b,s,h,d) output; ELEMENT units]
template <int STORE_BF16, int ADD_RES, int CAUSAL_SKIP, int K_CAUSAL, int FUSE_SILU, int CSPLIT>
__global__ __launch_bounds__(256) void gemm_bt(
    const u16* __restrict__ Ag, const u16* __restrict__ Bg, void* __restrict__ Cg,
    const float* __restrict__ Res, int K, int lda, int ldb, int ldc,
    long sAz, long sBz, long sCz, const int* __restrict__ mlimit) {
  int z = blockIdx.z;
  int m0 = blockIdx.y * 128, n0 = blockIdx.x * 128;
  if (mlimit && m0 >= mlimit[z]) return;
  if (CAUSAL_SKIP && n0 > m0 + 127) return;
  int kend = K_CAUSAL ? min(K, m0 + 128) : K;
  const u16* A = Ag + z * sAz;
  const u16* B = Bg + z * sBz;
  long cbase = CSPLIT ? ((long)(z >> 3) * ((long)S_ * H_) + (long)(z & 7) * sCz)
                      : (long)z * sCz;

  __shared__ __align__(16) u16 As[128 * 32];
  __shared__ __align__(16) u16 Bs[128 * 32];
  int tid = threadIdx.x;
  int lane = tid & 63, wave = tid >> 6;
  int wm = (wave & 1) * 64, wn = (wave >> 1) * 64;
  int la = lane & 15, qd = lane >> 4;
  int r0 = wave * 16 + (lane >> 2);
  int c0 = (lane & 3) * 8;

  const u16* ap0 = A + (long)(m0 + r0) * lda + c0;
  const u16* ap1 = A + (long)(m0 + 64 + r0) * lda + c0;
  const u16* bp0 = B + (long)(n0 + r0) * ldb + c0;
  const u16* bp1 = B + (long)(n0 + 64 + r0) * ldb + c0;
  u16* as0 = As + wave * 512;
  u16* as1 = As + 2048 + wave * 512;
  u16* bs0 = Bs + wave * 512;
  u16* bs1 = Bs + 2048 + wave * 512;

  f32x4 acc[4][4];
#pragma unroll
  for (int i = 0; i < 4; i++)
#pragma unroll
    for (int j = 0; j < 4; j++) acc[i][j] = (f32x4){0.f, 0.f, 0.f, 0.f};

  for (int k0 = 0; k0 < kend; k0 += 32) {
    __syncthreads();
    gll16(ap0 + k0, as0);
    gll16(ap1 + k0, as1);
    gll16(bp0 + k0, bs0);
    gll16(bp1 + k0, bs1);
    __syncthreads();
    bf16x8 af[4], bf[4];
#pragma unroll
    for (int i = 0; i < 4; i++)
      af[i] = *(const bf16x8*)(As + (wm + i * 16 + la) * 32 + qd * 8);
#pragma unroll
    for (int j = 0; j < 4; j++)
      bf[j] = *(const bf16x8*)(Bs + (wn + j * 16 + la) * 32 + qd * 8);
#pragma unroll
    for (int i = 0; i < 4; i++)
#pragma unroll
      for (int j = 0; j < 4; j++)
        acc[i][j] = __builtin_amdgcn_mfma_f32_16x16x32_bf16(af[i], bf[j], acc[i][j], 0, 0, 0);
  }

  if (FUSE_SILU) {
#pragma unroll
    for (int i = 0; i < 4; i++) {
#pragma unroll
      for (int jp = 0; jp < 2; jp++) {
        int hcol = ((n0 + wn) >> 1) + (jp << 4) + la;
#pragma unroll
        for (int r = 0; r < 4; r++) {
          int row = m0 + wm + i * 16 + qd * 4 + r;
          float g = acc[i][jp * 2][r], u = acc[i][jp * 2 + 1][r];
          float sg = g / (1.f + __expf(-g));
          ((u16*)Cg)[cbase + (long)row * ldc + hcol] = f2bf(sg * u);
        }
      }
    }
  } else {
#pragma unroll
    for (int i = 0; i < 4; i++) {
#pragma unroll
      for (int j = 0; j < 4; j++) {
        int col = n0 + wn + j * 16 + la;
#pragma unroll
        for (int r = 0; r < 4; r++) {
          int row = m0 + wm + i * 16 + qd * 4 + r;
          float v = acc[i][j][r];
          long ci = cbase + (long)row * ldc + col;
          if (ADD_RES) v += Res[(long)row * ldc + col];
          if (STORE_BF16) ((u16*)Cg)[ci] = f2bf(v);
          else ((float*)Cg)[ci] = v;
        }
      }
    }
  }
}

extern "C" void kernel_launch(void* const* d_in, const int* in_sizes, int n_in,
                              void* d_out, int out_size, void* d_ws, size_t ws_size,
                              hipStream_t stream) {
  const float* hidden = (const float*)d_in[0];
  const float* ln1w = (const float*)d_in[1];
  const float* ln2w = (const float*)d_in[2];
  const float* q_w = (const float*)d_in[3];
  const float* k_w = (const float*)d_in[4];
  const float* v_w = (const float*)d_in[5];
  const float* o_w = (const float*)d_in[6];
  const float* cosp = (const float*)d_in[7];
  const float* sinp = (const float*)d_in[8];
  const float* gate_w = (const float*)d_in[9];
  const float* eg_w = (const float*)d_in[10];
  const float* eu_w = (const float*)d_in[11];
  const float* ed_w = (const float*)d_in[12];
  const float* sg_w = (const float*)d_in[13];
  const float* su_w = (const float*)d_in[14];
  const float* sd_w = (const float*)d_in[15];
  float* out = (float*)d_out;

  char* w = (char*)d_ws;
  const size_t MB = 1u << 20;
  u16* qwb = (u16*)(w + 0 * MB);     // q,k,v,o bf16, 8MB
  u16* egu = (u16*)(w + 8 * MB);     // (E, 2*MI, H) interleaved g/u, 32MB
  u16* edb = (u16*)(w + 40 * MB);    // (E, H, MI) 16MB
  u16* sgu = (u16*)(w + 56 * MB);    // (2*SI, H) interleaved, 8MB
  u16* sdb = (u16*)(w + 64 * MB);    // (H, SI) 4MB
  float* x1 = (float*)(w + 68 * MB);
  u16* xn = (u16*)(w + 76 * MB);
  u16* attn = (u16*)(w + 80 * MB);
  int* cursor = (int*)(w + 84 * MB);
  int* arow = (int*)(w + 84 * MB + 1024);
  float* aw = (float*)(w + 84 * MB + 20 * 1024);
  int* eidx = (int*)(w + 84 * MB + 40 * 1024);
  // phase-1 arena
  float* qf = (float*)(w + 85 * MB);
  float* kf = (float*)(w + 93 * MB);
  float* vf = (float*)(w + 101 * MB);
  u16* qb = (u16*)(w + 109 * MB);
  u16* kb = (u16*)(w + 113 * MB);
  u16* vt = (u16*)(w + 117 * MB);
  float* scores = (float*)(w + 121 * MB);  // (16,S,S) fp32, 64MB (121-185)
  u16* P = (u16*)(w + 85 * MB);            // (16,S,S) bf16, 32MB (qf/kf/vf dead)
  // phase-2 arena
  u16* xg = (u16*)(w + 85 * MB);     // (E,CAP,H) 32MB
  u16* hbuf = (u16*)(w + 121 * MB);  // (E,CAP,MI) 32MB
  u16* y = (u16*)(w + 153 * MB);     // (E,CAP,H) 32MB
  u16* hs = (u16*)(w + 185 * MB);    // (T,SI) 8MB
  float* ys = (float*)(w + 193 * MB);  // (T,H) 8MB

  const long M1 = 1048576, M2 = 2097152, M8 = 8388608;

  // ---- weight conversions
  cvt4<<<4096, 256, 0, stream>>>(q_w, k_w, v_w, o_w, qwb);
  cvt_ilv<<<dim3(8192, 1, 2), 256, 0, stream>>>(eg_w, eu_w, egu, MI_, E_);
  cvt_plain<<<8192, 256, 0, stream>>>(ed_w, edb, M8);
  cvt_ilv<<<dim3(2048, 1, 2), 256, 0, stream>>>(sg_w, su_w, sgu, SI_, 1);
  cvt_plain<<<2048, 256, 0, stream>>>(sd_w, sdb, M2);

  // ---- attention
  rmsnorm_cvt<<<T_, 256, 0, stream>>>(hidden, ln1w, xn);
  gemm_bt<0, 0, 0, 0, 0, 0><<<dim3(8, 16, 3), 256, 0, stream>>>(
      xn, qwb, qf, nullptr, 1024, 1024, 1024, 1024, 0, M1, M2, nullptr);
  rope_cvt<<<dim3(8192, 1, 2), 256, 0, stream>>>(qf, cosp, sinp, qb);
  vtrans<<<dim3(32, 4, 16), dim3(32, 8), 0, stream>>>(vf, vt);

  // scores for both batches in one launch (z = b*8+h)
  gemm_bt<0, 0, 1, 0, 0, 0><<<dim3(8, 8, 16), 256, 0, stream>>>(
      qb, kb, scores, nullptr, 128, 128, 128, 1024,
      (long)S_ * HD_, (long)S_ * HD_, (long)S_ * S_, nullptr);
  softmax_causal<<<dim3(1024, 16), 256, 0, stream>>>(scores, P);
  gemm_bt<1, 0, 0, 1, 0, 1><<<dim3(1, 8, 16), 256, 0, stream>>>(
      P, vt, attn, nullptr, 1024, 1024, 1024, 1024,
      (long)S_ * S_, (long)HD_ * S_, (long)HD_, nullptr);
  gemm_bt<0, 1, 0, 0, 0, 0><<<dim3(8, 16, 1), 256, 0, stream>>>(
      attn, qwb + 3 * M1, x1, hidden, 1024, 1024, 1024, 1024, 0, 0, 0, nullptr);

  // ---- MoE (atomic-free routing)
  rmsnorm2_gate<<<T_, 256, 0, stream>>>(x1, ln2w, gate_w, xn, eidx, aw);
  route_scan<<<1, 256, 0, stream>>>(eidx, arow, cursor);
  gather_rows<<<4096, 256, 0, stream>>>(xn, arow, xg);
  gemm_bt<1, 0, 0, 0, 1, 0><<<dim3(16, 16, 8), 256, 0, stream>>>(
      xg, egu, hbuf, nullptr, 1024, 1024, 1024, MI_,
      (long)CAP_ * H_, (long)2 * MI_ * H_, (long)CAP_ * MI_, cursor);
  gemm_bt<1, 0, 0, 0, 0, 0><<<dim3(8, 16, 8), 256, 0, stream>>>(
      hbuf, edb, y, nullptr, 1024, 1024, 1024, 1024,
      (long)CAP_ * MI_, (long)H_ * MI_, (long)CAP_ * H_, cursor);
  // shared MLP
  gemm_bt<1, 0, 0, 0, 1, 0><<<dim3(32, 16, 1), 256, 0, stream>>>(
      xn, sgu, hs, nullptr, 1024, 1024, 1024, SI_, 0, 0, 0, nullptr);
  gemm_bt<0, 0, 0, 0, 0, 0><<<dim3(8, 16, 1), 256, 0, stream>>>(
      hs, sdb, ys, nullptr, 2048, 2048, 2048, 1024, 0, 0, 0, nullptr);

  final_combine<<<T_, 256, 0, stream>>>(x1, ys, y, arow, aw, out);
}

// Round 5
// 476.740 us; speedup vs baseline: 1.4489x; 1.0859x over previous
//
#include <hip/hip_runtime.h>

#define B_   2
#define S_   1024
#define H_   1024
#define NH_  8
#define HD_  128
#define E_   8
#define MI_  1024
#define SI_  2048
#define T_   2048
#define CAP_ 2048

typedef unsigned short u16;
typedef __attribute__((ext_vector_type(4))) float f32x4;
typedef __attribute__((ext_vector_type(4))) unsigned short u16x4;
typedef __attribute__((ext_vector_type(8))) __bf16 bf16x8;

__device__ __forceinline__ u16 f2bf(float f) {
  unsigned int u = __builtin_bit_cast(unsigned int, f);
  u = (u + 0x7fffu + ((u >> 16) & 1u)) >> 16;
  return (u16)u;
}
__device__ __forceinline__ float bf2f(u16 u) {
  return __builtin_bit_cast(float, (unsigned int)u << 16);
}
__device__ __forceinline__ float wave_sum(float v) {
#pragma unroll
  for (int o = 32; o; o >>= 1) v += __shfl_down(v, o, 64);
  return v;
}
// async global->LDS, 16B per lane, dest = wave-uniform base + lane*16
__device__ __forceinline__ void gll16(const u16* g, u16* l) {
  __builtin_amdgcn_global_load_lds((const __attribute__((address_space(1))) void*)g,
                                   (__attribute__((address_space(3))) void*)l, 16, 0, 0);
}

// ---------------- qkv+o weight convert: 4 x 1M fp32 -> contiguous bf16
__global__ void cvt4(const float* __restrict__ p0, const float* __restrict__ p1,
                     const float* __restrict__ p2, const float* __restrict__ p3,
                     u16* __restrict__ out) {
  int seg = blockIdx.x >> 10;
  long idx = ((long)(blockIdx.x & 1023) * 256 + threadIdx.x) * 4;
  const float* in = (seg == 0) ? p0 : (seg == 1) ? p1 : (seg == 2) ? p2 : p3;
  f32x4 v = *(const f32x4*)(in + idx);
  u16x4 r;
#pragma unroll
  for (int c = 0; c < 4; c++) r[c] = f2bf(v[c]);
  *(u16x4*)(out + (long)seg * 1048576 + idx) = r;
}

// ---------------- plain fp32->bf16
__global__ void cvt_plain(const float* __restrict__ in, u16* __restrict__ out, long n) {
  long i = ((long)blockIdx.x * 256 + threadIdx.x) * 4;
  if (i >= n) return;
  f32x4 v = *(const f32x4*)(in + i);
  u16x4 r;
#pragma unroll
  for (int c = 0; c < 4; c++) r[c] = f2bf(v[c]);
  *(u16x4*)(out + i) = r;
}

// ---------------- g/u 16-row interleave convert: out (nE, 2*rows, H)
__global__ void cvt_ilv(const float* __restrict__ g_in, const float* __restrict__ u_in,
                        u16* __restrict__ out, long rows, long nE) {
  long f = ((long)blockIdx.x * 256 + threadIdx.x) * 4;
  long per = rows * H_;
  if (f >= nE * per) return;
  const float* in = blockIdx.z ? u_in : g_in;
  long e = f / per;
  long rem = f - e * per;
  long i = rem >> 10;
  long hh = rem & 1023;
  long orow = (i >> 4) * 32 + (i & 15) + (blockIdx.z ? 16 : 0);
  f32x4 v = *(const f32x4*)(in + f);
  u16x4 r;
#pragma unroll
  for (int c = 0; c < 4; c++) r[c] = f2bf(v[c]);
  *(u16x4*)(out + (e * 2 * rows + orow) * H_ + hh) = r;
}

// ---------------- RMSNorm -> bf16
__global__ void rmsnorm_cvt(const float* __restrict__ x, const float* __restrict__ w,
                            u16* __restrict__ out) {
  int t = blockIdx.x, tid = threadIdx.x;
  f32x4 v = ((const f32x4*)(x + (long)t * H_))[tid];
  float ss = v[0]*v[0] + v[1]*v[1] + v[2]*v[2] + v[3]*v[3];
  __shared__ float red[4];
  float s = wave_sum(ss);
  if ((tid & 63) == 0) red[tid >> 6] = s;
  __syncthreads();
  float r = rsqrtf((red[0] + red[1] + red[2] + red[3]) * (1.0f / H_) + 1e-6f);
  f32x4 wv = ((const f32x4*)w)[tid];
  u16x4 o;
#pragma unroll
  for (int c = 0; c < 4; c++) o[c] = f2bf(v[c] * r * wv[c]);
  ((u16x4*)(out + (long)t * H_))[tid] = o;
}

// ---------------- fused RMSNorm2 + gate + top2 (no atomics)
__global__ void rmsnorm2_gate(const float* __restrict__ x1, const float* __restrict__ ln2w,
                              const float* __restrict__ gw, u16* __restrict__ xn,
                              int* __restrict__ eidx, float* __restrict__ aw) {
  int t = blockIdx.x, tid = threadIdx.x;
  int lane = tid & 63, wave = tid >> 6;
  f32x4 v = ((const f32x4*)(x1 + (long)t * H_))[tid];
  float ss = v[0]*v[0] + v[1]*v[1] + v[2]*v[2] + v[3]*v[3];
  __shared__ float redS[4];
  __shared__ float redE[4][E_];
  float s = wave_sum(ss);
  if (lane == 0) redS[wave] = s;
  __syncthreads();
  float r = rsqrtf((redS[0] + redS[1] + redS[2] + redS[3]) * (1.0f / H_) + 1e-6f);
  f32x4 wv = ((const f32x4*)ln2w)[tid];
  float xv[4];
  u16x4 o;
#pragma unroll
  for (int c = 0; c < 4; c++) { xv[c] = v[c] * r * wv[c]; o[c] = f2bf(xv[c]); }
  ((u16x4*)(xn + (long)t * H_))[tid] = o;
  float acc[E_];
#pragma unroll
  for (int e = 0; e < E_; e++) {
    f32x4 g = ((const f32x4*)(gw + (long)e * H_))[tid];
    acc[e] = xv[0]*g[0] + xv[1]*g[1] + xv[2]*g[2] + xv[3]*g[3];
  }
#pragma unroll
  for (int e = 0; e < E_; e++) acc[e] = wave_sum(acc[e]);
  if (lane == 0)
#pragma unroll
    for (int e = 0; e < E_; e++) redE[wave][e] = acc[e];
  __syncthreads();
  if (tid == 0) {
    float l[E_];
#pragma unroll
    for (int e = 0; e < E_; e++) l[e] = redE[0][e] + redE[1][e] + redE[2][e] + redE[3][e];
    float mx = l[0];
#pragma unroll
    for (int e = 1; e < E_; e++) mx = fmaxf(mx, l[e]);
    float p[E_], z = 0.f;
#pragma unroll
    for (int e = 0; e < E_; e++) { p[e] = __expf(l[e] - mx); z += p[e]; }
    int e0 = 0;
#pragma unroll
    for (int e = 1; e < E_; e++) if (p[e] > p[e0]) e0 = e;
    int e1 = (e0 == 0) ? 1 : 0;
#pragma unroll
    for (int e = 0; e < E_; e++) if (e != e0 && p[e] > p[e1]) e1 = e;
    float q0 = p[e0] / z, q1 = p[e1] / z;
    float invs = 1.0f / (q0 + q1 + 1e-20f);
    eidx[t * 2] = e0;
    eidx[t * 2 + 1] = e1;
    aw[t * 2] = q0 * invs;
    aw[t * 2 + 1] = q1 * invs;
  }
}

// ---------------- single-workgroup routing scan
__global__ __launch_bounds__(256) void route_scan(const int* __restrict__ eidx,
                                                  int* __restrict__ arow,
                                                  int* __restrict__ cursor) {
  __shared__ int sc[E_][256];
  int tid = threadIdx.x;
  unsigned c0 = 0, c1 = 0;
  int ebuf[16];
#pragma unroll
  for (int i = 0; i < 16; i++) {
    int e = eidx[tid * 16 + i];
    ebuf[i] = e;
    if (e < 4) c0 += 1u << (8 * e); else c1 += 1u << (8 * (e - 4));
  }
#pragma unroll
  for (int e = 0; e < E_; e++)
    sc[e][tid] = (e < 4) ? (int)((c0 >> (8 * e)) & 0xff) : (int)((c1 >> (8 * (e - 4))) & 0xff);
  __syncthreads();
  for (int st = 1; st < 256; st <<= 1) {
    int v[E_];
#pragma unroll
    for (int e = 0; e < E_; e++) v[e] = (tid >= st) ? sc[e][tid - st] : 0;
    __syncthreads();
#pragma unroll
    for (int e = 0; e < E_; e++) sc[e][tid] += v[e];
    __syncthreads();
  }
  if (tid == 255)
#pragma unroll
    for (int e = 0; e < E_; e++) cursor[e] = sc[e][255];
  int base[E_];
#pragma unroll
  for (int e = 0; e < E_; e++) {
    int own = (e < 4) ? (int)((c0 >> (8 * e)) & 0xff) : (int)((c1 >> (8 * (e - 4))) & 0xff);
    base[e] = sc[e][tid] - own;
  }
  __syncthreads();
#pragma unroll
  for (int e = 0; e < E_; e++) sc[e][tid] = base[e];
  __syncthreads();
  unsigned r0 = 0, r1 = 0;
#pragma unroll
  for (int i = 0; i < 16; i++) {
    int e = ebuf[i];
    int run = (e < 4) ? (int)((r0 >> (8 * e)) & 0xff) : (int)((r1 >> (8 * (e - 4))) & 0xff);
    arow[tid * 16 + i] = e * CAP_ + sc[e][tid] + run;
    if (e < 4) r0 += 1u << (8 * e); else r1 += 1u << (8 * (e - 4));
  }
}

// ---------------- RoPE + layout change (b,s,h,d)->(b,h,s,d), fp32->bf16; z picks q/k
__global__ void rope_cvt(const float* __restrict__ qf, const float* __restrict__ cs,
                         const float* __restrict__ sn, u16* __restrict__ qbb) {
  const float* q = qf + (long)blockIdx.z * 2097152;
  u16* qb = qbb + (long)blockIdx.z * 2097152;
  int rid = blockIdx.x * 2 + (threadIdx.x >> 7);
  int d = threadIdx.x & 127;
  int h = rid & (NH_ - 1);
  int bs = rid >> 3;
  int s = bs & (S_ - 1);
  int b = bs >> 10;
  long base = (long)rid * HD_;
  float v = q[base + d];
  float o = (d < 64) ? (-q[base + d + 64]) : q[base + d - 64];
  float res = v * cs[s * HD_ + d] + o * sn[s * HD_ + d];
  qb[((long)((b * NH_ + h) * S_ + s)) * HD_ + d] = f2bf(res);
}

// ---------------- V transpose: (b,s,h,d) fp32 -> (b,h,d,s) bf16
__global__ void vtrans(const float* __restrict__ v, u16* __restrict__ vt) {
  int bh = blockIdx.z, b = bh >> 3, h = bh & 7;
  int s0 = blockIdx.x * 32, d0 = blockIdx.y * 32;
  __shared__ u16 tile[32][33];
  for (int i = threadIdx.y; i < 32; i += 8) {
    float val = v[(((long)(b * S_ + s0 + i)) * NH_ + h) * HD_ + d0 + threadIdx.x];
    tile[i][threadIdx.x] = f2bf(val);
  }
  __syncthreads();
  for (int i = threadIdx.y; i < 32; i += 8) {
    vt[((long)bh * HD_ + d0 + i) * S_ + s0 + threadIdx.x] = tile[threadIdx.x][i];
  }
}

// ---------------- flash attention: one (b,h) x 64-row Q-tile per block, 4 waves.
// Online softmax; P C-layout -> A-layout via per-wave LDS strip.
__global__ __launch_bounds__(256) void flash_attn(
    const u16* __restrict__ qb, const u16* __restrict__ kb,
    const u16* __restrict__ vt, u16* __restrict__ attn) {
  int qt = blockIdx.x;   // 0..15
  int bh = blockIdx.y;   // b*8+h
  int b = bh >> 3, h = bh & 7;
  int tid = threadIdx.x;
  int wavei = tid >> 6, lane = tid & 63;
  int la = lane & 15, qd = lane >> 4;

  __shared__ __align__(16) u16 Ks[64 * 128];   // 16 KB: key rows x head-dim
  __shared__ __align__(16) u16 Vs[128 * 64];   // 16 KB: d rows x key cols (V^T)
  __shared__ __align__(16) u16 Ps[4][16 * 64]; // per-wave P strip

  // Q A-frags held in registers: rows qt*64 + wavei*16 + la
  bf16x8 qf[4];
  const u16* qrow = qb + ((long)bh * S_ + qt * 64 + wavei * 16 + la) * HD_;
#pragma unroll
  for (int ks = 0; ks < 4; ks++)
    qf[ks] = *(const bf16x8*)(qrow + ks * 32 + qd * 8);

  f32x4 oacc[8];
#pragma unroll
  for (int nf = 0; nf < 8; nf++) oacc[nf] = (f32x4){0.f, 0.f, 0.f, 0.f};
  float m_i[4], l_i[4];
#pragma unroll
  for (int r = 0; r < 4; r++) { m_i[r] = -1e30f; l_i[r] = 0.f; }

  const u16* Kbase = kb + (long)bh * S_ * HD_;
  const u16* Vbase = vt + (long)bh * HD_ * S_;
  const float scale = 0.08838834764831845f;
  u16* pw = (u16*)Ps[wavei];

  for (int j = 0; j <= qt; j++) {
    __syncthreads();
#pragma unroll
    for (int t = 0; t < 4; t++) {
      int blk = t * 4 + wavei;
      // K tile: 1KB block = 4 rows of 256B; lane -> row l>>4, chunk l&15
      gll16(Kbase + ((long)j * 64 + blk * 4 + (lane >> 4)) * 128 + (lane & 15) * 8,
            Ks + blk * 512);
      // V^T tile: 1KB block = 8 rows of 128B; lane -> row l>>3, chunk l&7
      gll16(Vbase + ((long)blk * 8 + (lane >> 3)) * 1024 + j * 64 + (lane & 7) * 8,
            Vs + blk * 512);
    }
    __syncthreads();

    // S = Q K^T  (16 rows x 64 cols per wave)
    f32x4 sacc[4];
#pragma unroll
    for (int jf = 0; jf < 4; jf++) sacc[jf] = (f32x4){0.f, 0.f, 0.f, 0.f};
#pragma unroll
    for (int ks = 0; ks < 4; ks++)
#pragma unroll
      for (int jf = 0; jf < 4; jf++) {
        bf16x8 kfrag = *(const bf16x8*)(Ks + (jf * 16 + la) * 128 + ks * 32 + qd * 8);
        sacc[jf] = __builtin_amdgcn_mfma_f32_16x16x32_bf16(qf[ks], kfrag, sacc[jf], 0, 0, 0);
      }

    // scale + causal mask
    float sv[4][4];
    int qglob = qt * 64 + wavei * 16 + qd * 4;
#pragma unroll
    for (int jf = 0; jf < 4; jf++) {
      int kglob = j * 64 + jf * 16 + la;
#pragma unroll
      for (int r = 0; r < 4; r++)
        sv[jf][r] = (kglob <= qglob + r) ? sacc[jf][r] * scale : -1e30f;
    }
    // row stats (rows live in 16-lane quad groups; xor<16 stays in-group)
    float mnew[4], alpha[4];
#pragma unroll
    for (int r = 0; r < 4; r++) {
      float mx = fmaxf(fmaxf(sv[0][r], sv[1][r]), fmaxf(sv[2][r], sv[3][r]));
#pragma unroll
      for (int o = 1; o < 16; o <<= 1) mx = fmaxf(mx, __shfl_xor(mx, o, 64));
      mnew[r] = fmaxf(m_i[r], mx);
      alpha[r] = __expf(m_i[r] - mnew[r]);
      m_i[r] = mnew[r];
    }
#pragma unroll
    for (int r = 0; r < 4; r++) {
      float sum = 0.f;
#pragma unroll
      for (int jf = 0; jf < 4; jf++) {
        float p = __expf(sv[jf][r] - mnew[r]);
        sv[jf][r] = p;
        sum += p;
      }
#pragma unroll
      for (int o = 1; o < 16; o <<= 1) sum += __shfl_xor(sum, o, 64);
      l_i[r] = l_i[r] * alpha[r] + sum;
    }
    // P C-layout -> LDS
#pragma unroll
    for (int jf = 0; jf < 4; jf++)
#pragma unroll
      for (int r = 0; r < 4; r++)
        pw[(qd * 4 + r) * 64 + jf * 16 + la] = f2bf(sv[jf][r]);
    // rescale O
#pragma unroll
    for (int nf = 0; nf < 8; nf++)
#pragma unroll
      for (int r = 0; r < 4; r++) oacc[nf][r] *= alpha[r];
    // O += P V   (A-frags from Ps, B-frags from Vs)
#pragma unroll
    for (int ks = 0; ks < 2; ks++) {
      bf16x8 pfrag = *(const bf16x8*)(pw + la * 64 + ks * 32 + qd * 8);
#pragma unroll
      for (int nf = 0; nf < 8; nf++) {
        bf16x8 vfrag = *(const bf16x8*)(Vs + (nf * 16 + la) * 64 + ks * 32 + qd * 8);
        oacc[nf] = __builtin_amdgcn_mfma_f32_16x16x32_bf16(pfrag, vfrag, oacc[nf], 0, 0, 0);
      }
    }
  }

  // epilogue: attn[(b, qg), h*128 + d] = O / l
  u16* arw = attn + ((long)b * S_ + qt * 64 + wavei * 16 + qd * 4) * H_ + h * HD_;
#pragma unroll
  for (int r = 0; r < 4; r++) {
    float inv = 1.0f / l_i[r];
#pragma unroll
    for (int nf = 0; nf < 8; nf++)
      arw[(long)r * H_ + nf * 16 + la] = f2bf(oacc[nf][r] * inv);
  }
}

// ---------------- gather token rows into per-expert slabs
__global__ void gather_rows(const u16* __restrict__ xn, const int* __restrict__ arow,
                            u16* __restrict__ xg) {
  int a = blockIdx.x;
  int t = a >> 1;
  int row = arow[a];
  u16x4 v = ((const u16x4*)(xn + (long)t * H_))[threadIdx.x];
  ((u16x4*)(xg + (long)row * H_))[threadIdx.x] = v;
}

// ---------------- final: out = x1 + shared + w0*y[r0] + w1*y[r1]
__global__ void final_combine(const float* __restrict__ x1, const float* __restrict__ ys,
                              const u16* __restrict__ y, const int* __restrict__ arow,
                              const float* __restrict__ aw, float* __restrict__ out) {
  int t = blockIdx.x;
  int i = threadIdx.x * 4;
  int r0 = arow[t * 2], r1 = arow[t * 2 + 1];
  float w0 = aw[t * 2], w1 = aw[t * 2 + 1];
  f32x4 a = *(const f32x4*)(x1 + (long)t * H_ + i);
  f32x4 b = *(const f32x4*)(ys + (long)t * H_ + i);
  u16x4 y0 = *(const u16x4*)(y + (long)r0 * H_ + i);
  u16x4 y1 = *(const u16x4*)(y + (long)r1 * H_ + i);
  f32x4 o;
#pragma unroll
  for (int c = 0; c < 4; c++)
    o[c] = a[c] + b[c] + w0 * bf2f(y0[c]) + w1 * bf2f(y1[c]);
  *(f32x4*)(out + (long)t * H_ + i) = o;
}

// ---------------- bf16 MFMA GEMM, m97 structure. MT = 128 or 64 (M-tile rows).
// C = A (MxK, k-contig) * B^T (NxK, k-contig). BK=32, unpadded LDS rows.
template <int MT, int STORE_BF16, int ADD_RES, int FUSE_SILU>
__global__ __launch_bounds__(256) void gemm_bt(
    const u16* __restrict__ Ag, const u16* __restrict__ Bg, void* __restrict__ Cg,
    const float* __restrict__ Res, int K, int lda, int ldb, int ldc,
    long sAz, long sBz, long sCz, const int* __restrict__ mlimit) {
  constexpr int MR = MT / 32;  // m-frags per wave (4 or 2)
  int z = blockIdx.z;
  int m0 = blockIdx.y * MT, n0 = blockIdx.x * 128;
  if (mlimit && m0 >= mlimit[z]) return;
  const u16* A = Ag + z * sAz;
  const u16* B = Bg + z * sBz;
  long cbase = (long)z * sCz;

  __shared__ __align__(16) u16 As[MT * 32];
  __shared__ __align__(16) u16 Bs[128 * 32];
  int tid = threadIdx.x;
  int lane = tid & 63, wave = tid >> 6;
  int wm = (wave & 1) * (MT / 2), wn = (wave >> 1) * 64;
  int la = lane & 15, qd = lane >> 4;
  int r0 = wave * 16 + (lane >> 2);
  int c0 = (lane & 3) * 8;

  const u16* ap0 = A + (long)(m0 + r0) * lda + c0;
  const u16* ap1 = A + (long)(m0 + 64 + r0) * lda + c0;
  const u16* bp0 = B + (long)(n0 + r0) * ldb + c0;
  const u16* bp1 = B + (long)(n0 + 64 + r0) * ldb + c0;
  u16* as0 = As + wave * 512;
  u16* as1 = As + 2048 + wave * 512;
  u16* bs0 = Bs + wave * 512;
  u16* bs1 = Bs + 2048 + wave * 512;

  f32x4 acc[MR][4];
#pragma unroll
  for (int i = 0; i < MR; i++)
#pragma unroll
    for (int j = 0; j < 4; j++) acc[i][j] = (f32x4){0.f, 0.f, 0.f, 0.f};

  for (int k0 = 0; k0 < K; k0 += 32) {
    __syncthreads();
    gll16(ap0 + k0, as0);
    if (MT == 128) gll16(ap1 + k0, as1);
    gll16(bp0 + k0, bs0);
    gll16(bp1 + k0, bs1);
    __syncthreads();
    bf16x8 af[MR], bf[4];
#pragma unroll
    for (int i = 0; i < MR; i++)
      af[i] = *(const bf16x8*)(As + (wm + i * 16 + la) * 32 + qd * 8);
#pragma unroll
    for (int j = 0; j < 4; j++)
      bf[j] = *(const bf16x8*)(Bs + (wn + j * 16 + la) * 32 + qd * 8);
#pragma unroll
    for (int i = 0; i < MR; i++)
#pragma unroll
      for (int j = 0; j < 4; j++)
        acc[i][j] = __builtin_amdgcn_mfma_f32_16x16x32_bf16(af[i], bf[j], acc[i][j], 0, 0, 0);
  }

  if (FUSE_SILU) {
#pragma unroll
    for (int i = 0; i < MR; i++) {
#pragma unroll
      for (int jp = 0; jp < 2; jp++) {
        int hcol = ((n0 + wn) >> 1) + (jp << 4) + la;
#pragma unroll
        for (int r = 0; r < 4; r++) {
          int row = m0 + wm + i * 16 + qd * 4 + r;
          float g = acc[i][jp * 2][r], u = acc[i][jp * 2 + 1][r];
          float sg = g / (1.f + __expf(-g));
          ((u16*)Cg)[cbase + (long)row * ldc + hcol] = f2bf(sg * u);
        }
      }
    }
  } else {
#pragma unroll
    for (int i = 0; i < MR; i++) {
#pragma unroll
      for (int j = 0; j < 4; j++) {
        int col = n0 + wn + j * 16 + la;
#pragma unroll
        for (int r = 0; r < 4; r++) {
          int row = m0 + wm + i * 16 + qd * 4 + r;
          float v = acc[i][j][r];
          long ci = cbase + (long)row * ldc + col;
          if (ADD_RES) v += Res[(long)row * ldc + col];
          if (STORE_BF16) ((u16*)Cg)[ci] = f2bf(v);
          else ((float*)Cg)[ci] = v;
        }
      }
    }
  }
}

extern "C" void kernel_launch(void* const* d_in, const int* in_sizes, int n_in,
                              void* d_out, int out_size, void* d_ws, size_t ws_size,
                              hipStream_t stream) {
  const float* hidden = (const float*)d_in[0];
  const float* ln1w = (const float*)d_in[1];
  const float* ln2w = (const float*)d_in[2];
  const float* q_w = (const float*)d_in[3];
  const float* k_w = (const float*)d_in[4];
  const float* v_w = (const float*)d_in[5];
  const float* o_w = (const float*)d_in[6];
  const float* cosp = (const float*)d_in[7];
  const float* sinp = (const float*)d_in[8];
  const float* gate_w = (const float*)d_in[9];
  const float* eg_w = (const float*)d_in[10];
  const float* eu_w = (const float*)d_in[11];
  const float* ed_w = (const float*)d_in[12];
  const float* sg_w = (const float*)d_in[13];
  const float* su_w = (const float*)d_in[14];
  const float* sd_w = (const float*)d_in[15];
  float* out = (float*)d_out;

  char* w = (char*)d_ws;
  const size_t MB = 1u << 20;
  u16* qwb = (u16*)(w + 0 * MB);     // q,k,v,o bf16, 8MB
  u16* egu = (u16*)(w + 8 * MB);     // (E, 2*MI, H) interleaved g/u, 32MB
  u16* edb = (u16*)(w + 40 * MB);    // (E, H, MI) 16MB
  u16* sgu = (u16*)(w + 56 * MB);    // (2*SI, H) interleaved, 8MB
  u16* sdb = (u16*)(w + 64 * MB);    // (H, SI) 4MB
  float* x1 = (float*)(w + 68 * MB);
  u16* xn = (u16*)(w + 76 * MB);
  u16* attn = (u16*)(w + 80 * MB);
  int* cursor = (int*)(w + 84 * MB);
  int* arow = (int*)(w + 84 * MB + 1024);
  float* aw = (float*)(w + 84 * MB + 20 * 1024);
  int* eidx = (int*)(w + 84 * MB + 40 * 1024);
  // phase-1 arena
  float* qf = (float*)(w + 85 * MB);
  float* kf = (float*)(w + 93 * MB);
  float* vf = (float*)(w + 101 * MB);
  u16* qb = (u16*)(w + 109 * MB);
  u16* kb = (u16*)(w + 113 * MB);
  u16* vt = (u16*)(w + 117 * MB);
  // phase-2 arena (aliases phase-1)
  u16* xg = (u16*)(w + 85 * MB);     // (E,CAP,H) 32MB
  u16* hbuf = (u16*)(w + 121 * MB);  // (E,CAP,MI) 32MB
  u16* y = (u16*)(w + 153 * MB);     // (E,CAP,H) 32MB
  u16* hs = (u16*)(w + 185 * MB);    // (T,SI) 8MB
  float* ys = (float*)(w + 193 * MB);  // (T,H) 8MB

  const long M1 = 1048576, M2 = 2097152, M8 = 8388608;

  // ---- weight conversions
  cvt4<<<4096, 256, 0, stream>>>(q_w, k_w, v_w, o_w, qwb);
  cvt_ilv<<<dim3(8192, 1, 2), 256, 0, stream>>>(eg_w, eu_w, egu, MI_, E_);
  cvt_plain<<<8192, 256, 0, stream>>>(ed_w, edb, M8);
  cvt_ilv<<<dim3(2048, 1, 2), 256, 0, stream>>>(sg_w, su_w, sgu, SI_, 1);
  cvt_plain<<<2048, 256, 0, stream>>>(sd_w, sdb, M2);

  // ---- attention
  rmsnorm_cvt<<<T_, 256, 0, stream>>>(hidden, ln1w, xn);
  gemm_bt<64, 0, 0, 0><<<dim3(8, 32, 3), 256, 0, stream>>>(
      xn, qwb, qf, nullptr, 1024, 1024, 1024, 1024, 0, M1, M2, nullptr);
  rope_cvt<<<dim3(8192, 1, 2), 256, 0, stream>>>(qf, cosp, sinp, qb);
  vtrans<<<dim3(32, 4, 16), dim3(32, 8), 0, stream>>>(vf, vt);
  flash_attn<<<dim3(16, 16), 256, 0, stream>>>(qb, kb, vt, attn);
  gemm_bt<64, 0, 1, 0><<<dim3(8, 32, 1), 256, 0, stream>>>(
      attn, qwb + 3 * M1, x1, hidden, 1024, 1024, 1024, 1024, 0, 0, 0, nullptr);

  // ---- MoE (atomic-free routing)
  rmsnorm2_gate<<<T_, 256, 0, stream>>>(x1, ln2w, gate_w, xn, eidx, aw);
  route_scan<<<1, 256, 0, stream>>>(eidx, arow, cursor);
  gather_rows<<<4096, 256, 0, stream>>>(xn, arow, xg);
  gemm_bt<128, 1, 0, 1><<<dim3(16, 16, 8), 256, 0, stream>>>(
      xg, egu, hbuf, nullptr, 1024, 1024, 1024, MI_,
      (long)CAP_ * H_, (long)2 * MI_ * H_, (long)CAP_ * MI_, cursor);
  gemm_bt<128, 1, 0, 0><<<dim3(8, 16, 8), 256, 0, stream>>>(
      hbuf, edb, y, nullptr, 1024, 1024, 1024, 1024,
      (long)CAP_ * MI_, (long)H_ * MI_, (long)CAP_ * H_, cursor);
  // shared MLP
  gemm_bt<128, 1, 0, 1><<<dim3(32, 16, 1), 256, 0, stream>>>(
      xn, sgu, hs, nullptr, 1024, 1024, 1024, SI_, 0, 0, 0, nullptr);
  gemm_bt<64, 0, 0, 0><<<dim3(8, 32, 1), 256, 0, stream>>>(
      hs, sdb, ys, nullptr, 2048, 2048, 2048, 1024, 0, 0, 0, nullptr);

  final_combine<<<T_, 256, 0, stream>>>(x1, ys, y, arow, aw, out);
}

// Round 6
// 474.730 us; speedup vs baseline: 1.4550x; 1.0042x over previous
//
#include <hip/hip_runtime.h>

#define B_   2
#define S_   1024
#define H_   1024
#define NH_  8
#define HD_  128
#define E_   8
#define MI_  1024
#define SI_  2048
#define T_   2048
#define CAP_ 2048

typedef unsigned short u16;
typedef __attribute__((ext_vector_type(4))) float f32x4;
typedef __attribute__((ext_vector_type(4))) unsigned short u16x4;
typedef __attribute__((ext_vector_type(8))) __bf16 bf16x8;

__device__ __forceinline__ u16 f2bf(float f) {
  unsigned int u = __builtin_bit_cast(unsigned int, f);
  u = (u + 0x7fffu + ((u >> 16) & 1u)) >> 16;
  return (u16)u;
}
__device__ __forceinline__ float bf2f(u16 u) {
  return __builtin_bit_cast(float, (unsigned int)u << 16);
}
__device__ __forceinline__ float wave_sum(float v) {
#pragma unroll
  for (int o = 32; o; o >>= 1) v += __shfl_down(v, o, 64);
  return v;
}
// async global->LDS, 16B per lane, dest = wave-uniform base + lane*16
__device__ __forceinline__ void gll16(const u16* g, u16* l) {
  __builtin_amdgcn_global_load_lds((const __attribute__((address_space(1))) void*)g,
                                   (__attribute__((address_space(3))) void*)l, 16, 0, 0);
}

// ---------------- qkv+o weight convert: 4 x 1M fp32 -> contiguous bf16
__global__ void cvt4(const float* __restrict__ p0, const float* __restrict__ p1,
                     const float* __restrict__ p2, const float* __restrict__ p3,
                     u16* __restrict__ out) {
  int seg = blockIdx.x >> 10;
  long idx = ((long)(blockIdx.x & 1023) * 256 + threadIdx.x) * 4;
  const float* in = (seg == 0) ? p0 : (seg == 1) ? p1 : (seg == 2) ? p2 : p3;
  f32x4 v = *(const f32x4*)(in + idx);
  u16x4 r;
#pragma unroll
  for (int c = 0; c < 4; c++) r[c] = f2bf(v[c]);
  *(u16x4*)(out + (long)seg * 1048576 + idx) = r;
}

// ---------------- plain fp32->bf16
__global__ void cvt_plain(const float* __restrict__ in, u16* __restrict__ out, long n) {
  long i = ((long)blockIdx.x * 256 + threadIdx.x) * 4;
  if (i >= n) return;
  f32x4 v = *(const f32x4*)(in + i);
  u16x4 r;
#pragma unroll
  for (int c = 0; c < 4; c++) r[c] = f2bf(v[c]);
  *(u16x4*)(out + i) = r;
}

// ---------------- g/u 16-row interleave convert: out (nE, 2*rows, H)
__global__ void cvt_ilv(const float* __restrict__ g_in, const float* __restrict__ u_in,
                        u16* __restrict__ out, long rows, long nE) {
  long f = ((long)blockIdx.x * 256 + threadIdx.x) * 4;
  long per = rows * H_;
  if (f >= nE * per) return;
  const float* in = blockIdx.z ? u_in : g_in;
  long e = f / per;
  long rem = f - e * per;
  long i = rem >> 10;
  long hh = rem & 1023;
  long orow = (i >> 4) * 32 + (i & 15) + (blockIdx.z ? 16 : 0);
  f32x4 v = *(const f32x4*)(in + f);
  u16x4 r;
#pragma unroll
  for (int c = 0; c < 4; c++) r[c] = f2bf(v[c]);
  *(u16x4*)(out + (e * 2 * rows + orow) * H_ + hh) = r;
}

// ---------------- RMSNorm -> bf16
__global__ void rmsnorm_cvt(const float* __restrict__ x, const float* __restrict__ w,
                            u16* __restrict__ out) {
  int t = blockIdx.x, tid = threadIdx.x;
  f32x4 v = ((const f32x4*)(x + (long)t * H_))[tid];
  float ss = v[0]*v[0] + v[1]*v[1] + v[2]*v[2] + v[3]*v[3];
  __shared__ float red[4];
  float s = wave_sum(ss);
  if ((tid & 63) == 0) red[tid >> 6] = s;
  __syncthreads();
  float r = rsqrtf((red[0] + red[1] + red[2] + red[3]) * (1.0f / H_) + 1e-6f);
  f32x4 wv = ((const f32x4*)w)[tid];
  u16x4 o;
#pragma unroll
  for (int c = 0; c < 4; c++) o[c] = f2bf(v[c] * r * wv[c]);
  ((u16x4*)(out + (long)t * H_))[tid] = o;
}

// ---------------- fused RMSNorm2 + gate + top2 (no atomics)
__global__ void rmsnorm2_gate(const float* __restrict__ x1, const float* __restrict__ ln2w,
                              const float* __restrict__ gw, u16* __restrict__ xn,
                              int* __restrict__ eidx, float* __restrict__ aw) {
  int t = blockIdx.x, tid = threadIdx.x;
  int lane = tid & 63, wave = tid >> 6;
  f32x4 v = ((const f32x4*)(x1 + (long)t * H_))[tid];
  float ss = v[0]*v[0] + v[1]*v[1] + v[2]*v[2] + v[3]*v[3];
  __shared__ float redS[4];
  __shared__ float redE[4][E_];
  float s = wave_sum(ss);
  if (lane == 0) redS[wave] = s;
  __syncthreads();
  float r = rsqrtf((redS[0] + redS[1] + redS[2] + redS[3]) * (1.0f / H_) + 1e-6f);
  f32x4 wv = ((const f32x4*)ln2w)[tid];
  float xv[4];
  u16x4 o;
#pragma unroll
  for (int c = 0; c < 4; c++) { xv[c] = v[c] * r * wv[c]; o[c] = f2bf(xv[c]); }
  ((u16x4*)(xn + (long)t * H_))[tid] = o;
  float acc[E_];
#pragma unroll
  for (int e = 0; e < E_; e++) {
    f32x4 g = ((const f32x4*)(gw + (long)e * H_))[tid];
    acc[e] = xv[0]*g[0] + xv[1]*g[1] + xv[2]*g[2] + xv[3]*g[3];
  }
#pragma unroll
  for (int e = 0; e < E_; e++) acc[e] = wave_sum(acc[e]);
  if (lane == 0)
#pragma unroll
    for (int e = 0; e < E_; e++) redE[wave][e] = acc[e];
  __syncthreads();
  if (tid == 0) {
    float l[E_];
#pragma unroll
    for (int e = 0; e < E_; e++) l[e] = redE[0][e] + redE[1][e] + redE[2][e] + redE[3][e];
    float mx = l[0];
#pragma unroll
    for (int e = 1; e < E_; e++) mx = fmaxf(mx, l[e]);
    float p[E_], z = 0.f;
#pragma unroll
    for (int e = 0; e < E_; e++) { p[e] = __expf(l[e] - mx); z += p[e]; }
    int e0 = 0;
#pragma unroll
    for (int e = 1; e < E_; e++) if (p[e] > p[e0]) e0 = e;
    int e1 = (e0 == 0) ? 1 : 0;
#pragma unroll
    for (int e = 0; e < E_; e++) if (e != e0 && p[e] > p[e1]) e1 = e;
    float q0 = p[e0] / z, q1 = p[e1] / z;
    float invs = 1.0f / (q0 + q1 + 1e-20f);
    eidx[t * 2] = e0;
    eidx[t * 2 + 1] = e1;
    aw[t * 2] = q0 * invs;
    aw[t * 2 + 1] = q1 * invs;
  }
}

// ---------------- single-workgroup routing scan
__global__ __launch_bounds__(256) void route_scan(const int* __restrict__ eidx,
                                                  int* __restrict__ arow,
                                                  int* __restrict__ cursor) {
  __shared__ int sc[E_][256];
  int tid = threadIdx.x;
  unsigned c0 = 0, c1 = 0;
  int ebuf[16];
#pragma unroll
  for (int i = 0; i < 16; i++) {
    int e = eidx[tid * 16 + i];
    ebuf[i] = e;
    if (e < 4) c0 += 1u << (8 * e); else c1 += 1u << (8 * (e - 4));
  }
#pragma unroll
  for (int e = 0; e < E_; e++)
    sc[e][tid] = (e < 4) ? (int)((c0 >> (8 * e)) & 0xff) : (int)((c1 >> (8 * (e - 4))) & 0xff);
  __syncthreads();
  for (int st = 1; st < 256; st <<= 1) {
    int v[E_];
#pragma unroll
    for (int e = 0; e < E_; e++) v[e] = (tid >= st) ? sc[e][tid - st] : 0;
    __syncthreads();
#pragma unroll
    for (int e = 0; e < E_; e++) sc[e][tid] += v[e];
    __syncthreads();
  }
  if (tid == 255)
#pragma unroll
    for (int e = 0; e < E_; e++) cursor[e] = sc[e][255];
  int base[E_];
#pragma unroll
  for (int e = 0; e < E_; e++) {
    int own = (e < 4) ? (int)((c0 >> (8 * e)) & 0xff) : (int)((c1 >> (8 * (e - 4))) & 0xff);
    base[e] = sc[e][tid] - own;
  }
  __syncthreads();
#pragma unroll
  for (int e = 0; e < E_; e++) sc[e][tid] = base[e];
  __syncthreads();
  unsigned r0 = 0, r1 = 0;
#pragma unroll
  for (int i = 0; i < 16; i++) {
    int e = ebuf[i];
    int run = (e < 4) ? (int)((r0 >> (8 * e)) & 0xff) : (int)((r1 >> (8 * (e - 4))) & 0xff);
    arow[tid * 16 + i] = e * CAP_ + sc[e][tid] + run;
    if (e < 4) r0 += 1u << (8 * e); else r1 += 1u << (8 * (e - 4));
  }
}

// ---------------- RoPE + layout change (b,s,h,d)->(b,h,s,d), fp32->bf16; z picks q/k
__global__ void rope_cvt(const float* __restrict__ qf, const float* __restrict__ cs,
                         const float* __restrict__ sn, u16* __restrict__ qbb) {
  const float* q = qf + (long)blockIdx.z * 2097152;
  u16* qb = qbb + (long)blockIdx.z * 2097152;
  int rid = blockIdx.x * 2 + (threadIdx.x >> 7);
  int d = threadIdx.x & 127;
  int h = rid & (NH_ - 1);
  int bs = rid >> 3;
  int s = bs & (S_ - 1);
  int b = bs >> 10;
  long base = (long)rid * HD_;
  float v = q[base + d];
  float o = (d < 64) ? (-q[base + d + 64]) : q[base + d - 64];
  float res = v * cs[s * HD_ + d] + o * sn[s * HD_ + d];
  qb[((long)((b * NH_ + h) * S_ + s)) * HD_ + d] = f2bf(res);
}

// ---------------- V transpose: (b,s,h,d) fp32 -> (b,h,d,s) bf16
__global__ void vtrans(const float* __restrict__ v, u16* __restrict__ vt) {
  int bh = blockIdx.z, b = bh >> 3, h = bh & 7;
  int s0 = blockIdx.x * 32, d0 = blockIdx.y * 32;
  __shared__ u16 tile[32][33];
  for (int i = threadIdx.y; i < 32; i += 8) {
    float val = v[(((long)(b * S_ + s0 + i)) * NH_ + h) * HD_ + d0 + threadIdx.x];
    tile[i][threadIdx.x] = f2bf(val);
  }
  __syncthreads();
  for (int i = threadIdx.y; i < 32; i += 8) {
    vt[((long)bh * HD_ + d0 + i) * S_ + s0 + threadIdx.x] = tile[threadIdx.x][i];
  }
}

// ---------------- split-K flash attention partials.
// Work item: (bh, qt, chunk of <=4 K-tiles). 40 items x 16 bh = 640 blocks.
// Writes unnormalized O (fp32) + per-row m,l. XOR-swizzled LDS (chunk ^= row&7).
__global__ __launch_bounds__(256) void flash_part(
    const u16* __restrict__ qb, const u16* __restrict__ kb,
    const u16* __restrict__ vt, float* __restrict__ Po,
    float* __restrict__ Pm, float* __restrict__ Pl) {
  int item = blockIdx.x;  // 0..39
  int bh = blockIdx.y;
  int qt, ch;
  if (item < 4)       { qt = item;                    ch = 0; }
  else if (item < 12) { qt = 4 + ((item - 4) >> 1);   ch = (item - 4) & 1; }
  else if (item < 24) { qt = 8 + (item - 12) / 3;     ch = (item - 12) % 3; }
  else                { qt = 12 + ((item - 24) >> 2); ch = (item - 24) & 3; }
  int j0 = ch * 4, j1 = min(j0 + 4, qt + 1);

  int tid = threadIdx.x;
  int wavei = tid >> 6, lane = tid & 63;
  int la = lane & 15, qd = lane >> 4;

  __shared__ __align__(16) u16 Ks[64 * 128];   // key rows x head-dim, swizzled
  __shared__ __align__(16) u16 Vs[128 * 64];   // d rows x key cols (V^T), swizzled
  __shared__ __align__(16) u16 Ps[4][16 * 64]; // per-wave P strip, swizzled

  bf16x8 qf[4];
  const u16* qrow = qb + ((long)bh * S_ + qt * 64 + wavei * 16 + la) * HD_;
#pragma unroll
  for (int ks = 0; ks < 4; ks++)
    qf[ks] = *(const bf16x8*)(qrow + ks * 32 + qd * 8);

  f32x4 oacc[8];
#pragma unroll
  for (int nf = 0; nf < 8; nf++) oacc[nf] = (f32x4){0.f, 0.f, 0.f, 0.f};
  float m_i[4], l_i[4];
#pragma unroll
  for (int r = 0; r < 4; r++) { m_i[r] = -1e30f; l_i[r] = 0.f; }

  const u16* Kbase = kb + (long)bh * S_ * HD_;
  const u16* Vbase = vt + (long)bh * HD_ * S_;
  const float scale = 0.08838834764831845f;
  u16* pw = (u16*)Ps[wavei];
  int swz = la & 7;

  for (int j = j0; j < j1; j++) {
    __syncthreads();
#pragma unroll
    for (int t = 0; t < 4; t++) {
      int blk = t * 4 + wavei;
      int kr = blk * 4 + (lane >> 4);              // K row 0..63
      int kc = (lane & 15) ^ (kr & 7);             // swizzled source chunk
      gll16(Kbase + ((long)j * 64 + kr) * 128 + kc * 8, Ks + blk * 512);
      int vr = blk * 8 + (lane >> 3);              // V^T row (d) 0..127
      int vc = (lane & 7) ^ (vr & 7);
      gll16(Vbase + (long)vr * 1024 + j * 64 + vc * 8, Vs + blk * 512);
    }
    __syncthreads();

    // S = Q K^T (16 rows x 64 cols per wave)
    f32x4 sacc[4];
#pragma unroll
    for (int jf = 0; jf < 4; jf++) sacc[jf] = (f32x4){0.f, 0.f, 0.f, 0.f};
#pragma unroll
    for (int ks = 0; ks < 4; ks++)
#pragma unroll
      for (int jf = 0; jf < 4; jf++) {
        bf16x8 kfrag = *(const bf16x8*)(Ks + (jf * 16 + la) * 128 + ((ks * 4 + qd) ^ swz) * 8);
        sacc[jf] = __builtin_amdgcn_mfma_f32_16x16x32_bf16(qf[ks], kfrag, sacc[jf], 0, 0, 0);
      }

    float sv[4][4];
    int qglob = qt * 64 + wavei * 16 + qd * 4;
#pragma unroll
    for (int jf = 0; jf < 4; jf++) {
      int kglob = j * 64 + jf * 16 + la;
#pragma unroll
      for (int r = 0; r < 4; r++)
        sv[jf][r] = (kglob <= qglob + r) ? sacc[jf][r] * scale : -1e30f;
    }
    float mnew[4], alpha[4];
#pragma unroll
    for (int r = 0; r < 4; r++) {
      float mx = fmaxf(fmaxf(sv[0][r], sv[1][r]), fmaxf(sv[2][r], sv[3][r]));
#pragma unroll
      for (int o = 1; o < 16; o <<= 1) mx = fmaxf(mx, __shfl_xor(mx, o, 64));
      mnew[r] = fmaxf(m_i[r], mx);
      alpha[r] = __expf(m_i[r] - mnew[r]);
      m_i[r] = mnew[r];
    }
#pragma unroll
    for (int r = 0; r < 4; r++) {
      float sum = 0.f;
#pragma unroll
      for (int jf = 0; jf < 4; jf++) {
        float p = __expf(sv[jf][r] - mnew[r]);
        sv[jf][r] = p;
        sum += p;
      }
#pragma unroll
      for (int o = 1; o < 16; o <<= 1) sum += __shfl_xor(sum, o, 64);
      l_i[r] = l_i[r] * alpha[r] + sum;
    }
    // P C-layout -> LDS (swizzled chunks)
#pragma unroll
    for (int jf = 0; jf < 4; jf++)
#pragma unroll
      for (int r = 0; r < 4; r++) {
        int rp = qd * 4 + r;
        int e = jf * 16 + la;
        pw[rp * 64 + (((e >> 3) ^ (rp & 7)) << 3) + (e & 7)] = f2bf(sv[jf][r]);
      }
#pragma unroll
    for (int nf = 0; nf < 8; nf++)
#pragma unroll
      for (int r = 0; r < 4; r++) oacc[nf][r] *= alpha[r];
    // O += P V
#pragma unroll
    for (int ks = 0; ks < 2; ks++) {
      bf16x8 pfrag = *(const bf16x8*)(pw + la * 64 + ((ks * 4 + qd) ^ swz) * 8);
#pragma unroll
      for (int nf = 0; nf < 8; nf++) {
        bf16x8 vfrag = *(const bf16x8*)(Vs + (nf * 16 + la) * 64 + (((ks * 4 + qd) & 7) ^ swz) * 8);
        oacc[nf] = __builtin_amdgcn_mfma_f32_16x16x32_bf16(pfrag, vfrag, oacc[nf], 0, 0, 0);
      }
    }
  }

  int pidx = (bh * 16 + qt) * 4 + ch;
  int rowb = wavei * 16 + qd * 4;
  float* pob = Po + ((long)pidx * 64 + rowb) * 128;
#pragma unroll
  for (int r = 0; r < 4; r++)
#pragma unroll
    for (int nf = 0; nf < 8; nf++)
      pob[(long)r * 128 + nf * 16 + la] = oacc[nf][r];
  if (la == 0)
#pragma unroll
    for (int r = 0; r < 4; r++) {
      Pm[pidx * 64 + rowb + r] = m_i[r];
      Pl[pidx * 64 + rowb + r] = l_i[r];
    }
}

// ---------------- merge split-K partials -> attn (b,s,h*128+d) bf16
__global__ __launch_bounds__(256) void attn_merge(
    const float* __restrict__ Po, const float* __restrict__ Pm,
    const float* __restrict__ Pl, u16* __restrict__ attn) {
  int qt = blockIdx.x, bh = blockIdx.y;
  int b = bh >> 3, h = bh & 7;
  int nch = (qt >> 2) + 1;
  int t = threadIdx.x;
  int row = t >> 2, cg = (t & 3) * 32;
  long base = (long)(bh * 16 + qt) * 4;
  float mv[4], wv[4];
  float M = -1e30f;
  for (int c = 0; c < nch; c++) { mv[c] = Pm[(base + c) * 64 + row]; M = fmaxf(M, mv[c]); }
  float L = 0.f;
  for (int c = 0; c < nch; c++) { wv[c] = __expf(mv[c] - M); L += wv[c] * Pl[(base + c) * 64 + row]; }
  float inv = 1.0f / L;
  f32x4 o[8];
#pragma unroll
  for (int k = 0; k < 8; k++) o[k] = (f32x4){0.f, 0.f, 0.f, 0.f};
  for (int c = 0; c < nch; c++) {
    const f32x4* src = (const f32x4*)(Po + ((base + c) * 64 + row) * 128 + cg);
#pragma unroll
    for (int k = 0; k < 8; k++) o[k] += src[k] * wv[c];
  }
  u16* dst = attn + ((long)b * S_ + qt * 64 + row) * H_ + h * HD_ + cg;
#pragma unroll
  for (int k = 0; k < 8; k++) {
    u16x4 ov;
#pragma unroll
    for (int c = 0; c < 4; c++) ov[c] = f2bf(o[k][c] * inv);
    ((u16x4*)dst)[k] = ov;
  }
}

// ---------------- gather token rows into per-expert slabs
__global__ void gather_rows(const u16* __restrict__ xn, const int* __restrict__ arow,
                            u16* __restrict__ xg) {
  int a = blockIdx.x;
  int t = a >> 1;
  int row = arow[a];
  u16x4 v = ((const u16x4*)(xn + (long)t * H_))[threadIdx.x];
  ((u16x4*)(xg + (long)row * H_))[threadIdx.x] = v;
}

// ---------------- final: out = x1 + shared + w0*y[r0] + w1*y[r1]
__global__ void final_combine(const float* __restrict__ x1, const float* __restrict__ ys,
                              const u16* __restrict__ y, const int* __restrict__ arow,
                              const float* __restrict__ aw, float* __restrict__ out) {
  int t = blockIdx.x;
  int i = threadIdx.x * 4;
  int r0 = arow[t * 2], r1 = arow[t * 2 + 1];
  float w0 = aw[t * 2], w1 = aw[t * 2 + 1];
  f32x4 a = *(const f32x4*)(x1 + (long)t * H_ + i);
  f32x4 b = *(const f32x4*)(ys + (long)t * H_ + i);
  u16x4 y0 = *(const u16x4*)(y + (long)r0 * H_ + i);
  u16x4 y1 = *(const u16x4*)(y + (long)r1 * H_ + i);
  f32x4 o;
#pragma unroll
  for (int c = 0; c < 4; c++)
    o[c] = a[c] + b[c] + w0 * bf2f(y0[c]) + w1 * bf2f(y1[c]);
  *(f32x4*)(out + (long)t * H_ + i) = o;
}

// ---------------- bf16 MFMA GEMM, m97 structure. MT = 128 or 64 (M-tile rows).
template <int MT, int STORE_BF16, int ADD_RES, int FUSE_SILU>
__global__ __launch_bounds__(256) void gemm_bt(
    const u16* __restrict__ Ag, const u16* __restrict__ Bg, void* __restrict__ Cg,
    const float* __restrict__ Res, int K, int lda, int ldb, int ldc,
    long sAz, long sBz, long sCz, const int* __restrict__ mlimit) {
  constexpr int MR = MT / 32;
  int z = blockIdx.z;
  int m0 = blockIdx.y * MT, n0 = blockIdx.x * 128;
  if (mlimit && m0 >= mlimit[z]) return;
  const u16* A = Ag + z * sAz;
  const u16* B = Bg + z * sBz;
  long cbase = (long)z * sCz;

  __shared__ __align__(16) u16 As[MT * 32];
  __shared__ __align__(16) u16 Bs[128 * 32];
  int tid = threadIdx.x;
  int lane = tid & 63, wave = tid >> 6;
  int wm = (wave & 1) * (MT / 2), wn = (wave >> 1) * 64;
  int la = lane & 15, qd = lane >> 4;
  int r0 = wave * 16 + (lane >> 2);
  int c0 = (lane & 3) * 8;

  const u16* ap0 = A + (long)(m0 + r0) * lda + c0;
  const u16* ap1 = A + (long)(m0 + 64 + r0) * lda + c0;
  const u16* bp0 = B + (long)(n0 + r0) * ldb + c0;
  const u16* bp1 = B + (long)(n0 + 64 + r0) * ldb + c0;
  u16* as0 = As + wave * 512;
  u16* as1 = As + 2048 + wave * 512;
  u16* bs0 = Bs + wave * 512;
  u16* bs1 = Bs + 2048 + wave * 512;

  f32x4 acc[MR][4];
#pragma unroll
  for (int i = 0; i < MR; i++)
#pragma unroll
    for (int j = 0; j < 4; j++) acc[i][j] = (f32x4){0.f, 0.f, 0.f, 0.f};

  for (int k0 = 0; k0 < K; k0 += 32) {
    __syncthreads();
    gll16(ap0 + k0, as0);
    if (MT == 128) gll16(ap1 + k0, as1);
    gll16(bp0 + k0, bs0);
    gll16(bp1 + k0, bs1);
    __syncthreads();
    bf16x8 af[MR], bf[4];
#pragma unroll
    for (int i = 0; i < MR; i++)
      af[i] = *(const bf16x8*)(As + (wm + i * 16 + la) * 32 + qd * 8);
#pragma unroll
    for (int j = 0; j < 4; j++)
      bf[j] = *(const bf16x8*)(Bs + (wn + j * 16 + la) * 32 + qd * 8);
#pragma unroll
    for (int i = 0; i < MR; i++)
#pragma unroll
      for (int j = 0; j < 4; j++)
        acc[i][j] = __builtin_amdgcn_mfma_f32_16x16x32_bf16(af[i], bf[j], acc[i][j], 0, 0, 0);
  }

  if (FUSE_SILU) {
#pragma unroll
    for (int i = 0; i < MR; i++) {
#pragma unroll
      for (int jp = 0; jp < 2; jp++) {
        int hcol = ((n0 + wn) >> 1) + (jp << 4) + la;
#pragma unroll
        for (int r = 0; r < 4; r++) {
          int row = m0 + wm + i * 16 + qd * 4 + r;
          float g = acc[i][jp * 2][r], u = acc[i][jp * 2 + 1][r];
          float sg = g / (1.f + __expf(-g));
          ((u16*)Cg)[cbase + (long)row * ldc + hcol] = f2bf(sg * u);
        }
      }
    }
  } else {
#pragma unroll
    for (int i = 0; i < MR; i++) {
#pragma unroll
      for (int j = 0; j < 4; j++) {
        int col = n0 + wn + j * 16 + la;
#pragma unroll
        for (int r = 0; r < 4; r++) {
          int row = m0 + wm + i * 16 + qd * 4 + r;
          float v = acc[i][j][r];
          long ci = cbase + (long)row * ldc + col;
          if (ADD_RES) v += Res[(long)row * ldc + col];
          if (STORE_BF16) ((u16*)Cg)[ci] = f2bf(v);
          else ((float*)Cg)[ci] = v;
        }
      }
    }
  }
}

extern "C" void kernel_launch(void* const* d_in, const int* in_sizes, int n_in,
                              void* d_out, int out_size, void* d_ws, size_t ws_size,
                              hipStream_t stream) {
  const float* hidden = (const float*)d_in[0];
  const float* ln1w = (const float*)d_in[1];
  const float* ln2w = (const float*)d_in[2];
  const float* q_w = (const float*)d_in[3];
  const float* k_w = (const float*)d_in[4];
  const float* v_w = (const float*)d_in[5];
  const float* o_w = (const float*)d_in[6];
  const float* cosp = (const float*)d_in[7];
  const float* sinp = (const float*)d_in[8];
  const float* gate_w = (const float*)d_in[9];
  const float* eg_w = (const float*)d_in[10];
  const float* eu_w = (const float*)d_in[11];
  const float* ed_w = (const float*)d_in[12];
  const float* sg_w = (const float*)d_in[13];
  const float* su_w = (const float*)d_in[14];
  const float* sd_w = (const float*)d_in[15];
  float* out = (float*)d_out;

  char* w = (char*)d_ws;
  const size_t MB = 1u << 20;
  u16* qwb = (u16*)(w + 0 * MB);     // q,k,v,o bf16, 8MB
  u16* egu = (u16*)(w + 8 * MB);     // (E, 2*MI, H) interleaved g/u, 32MB
  u16* edb = (u16*)(w + 40 * MB);    // (E, H, MI) 16MB
  u16* sgu = (u16*)(w + 56 * MB);    // (2*SI, H) interleaved, 8MB
  u16* sdb = (u16*)(w + 64 * MB);    // (H, SI) 4MB
  float* x1 = (float*)(w + 68 * MB);
  u16* xn = (u16*)(w + 76 * MB);
  u16* attn = (u16*)(w + 80 * MB);
  int* cursor = (int*)(w + 84 * MB);
  int* arow = (int*)(w + 84 * MB + 1024);
  float* aw = (float*)(w + 84 * MB + 20 * 1024);
  int* eidx = (int*)(w + 84 * MB + 40 * 1024);
  // phase-1 arena
  float* qf = (float*)(w + 85 * MB);
  float* kf = (float*)(w + 93 * MB);
  float* vf = (float*)(w + 101 * MB);
  u16* qb = (u16*)(w + 109 * MB);
  u16* kb = (u16*)(w + 113 * MB);
  u16* vt = (u16*)(w + 117 * MB);
  float* Po = (float*)(w + 121 * MB);   // 1024 x 64 x 128 fp32 = 33.5MB
  float* Pm = (float*)(w + 155 * MB);   // 256KB
  float* Pl = (float*)(w + 156 * MB);   // 256KB
  // phase-2 arena (aliases phase-1)
  u16* xg = (u16*)(w + 85 * MB);     // (E,CAP,H) 32MB
  u16* hbuf = (u16*)(w + 121 * MB);  // (E,CAP,MI) 32MB
  u16* y = (u16*)(w + 157 * MB);     // (E,CAP,H) 32MB
  u16* hs = (u16*)(w + 189 * MB);    // (T,SI) 8MB
  float* ys = (float*)(w + 197 * MB);  // (T,H) 8MB

  const long M1 = 1048576, M2 = 2097152, M8 = 8388608;

  // ---- weight conversions
  cvt4<<<4096, 256, 0, stream>>>(q_w, k_w, v_w, o_w, qwb);
  cvt_ilv<<<dim3(8192, 1, 2), 256, 0, stream>>>(eg_w, eu_w, egu, MI_, E_);
  cvt_plain<<<8192, 256, 0, stream>>>(ed_w, edb, M8);
  cvt_ilv<<<dim3(2048, 1, 2), 256, 0, stream>>>(sg_w, su_w, sgu, SI_, 1);
  cvt_plain<<<2048, 256, 0, stream>>>(sd_w, sdb, M2);

  // ---- attention
  rmsnorm_cvt<<<T_, 256, 0, stream>>>(hidden, ln1w, xn);
  gemm_bt<64, 0, 0, 0><<<dim3(8, 32, 3), 256, 0, stream>>>(
      xn, qwb, qf, nullptr, 1024, 1024, 1024, 1024, 0, M1, M2, nullptr);
  rope_cvt<<<dim3(8192, 1, 2), 256, 0, stream>>>(qf, cosp, sinp, qb);
  vtrans<<<dim3(32, 4, 16), dim3(32, 8), 0, stream>>>(vf, vt);
  flash_part<<<dim3(40, 16), 256, 0, stream>>>(qb, kb, vt, Po, Pm, Pl);
  attn_merge<<<dim3(16, 16), 256, 0, stream>>>(Po, Pm, Pl, attn);
  gemm_bt<64, 0, 1, 0><<<dim3(8, 32, 1), 256, 0, stream>>>(
      attn, qwb + 3 * M1, x1, hidden, 1024, 1024, 1024, 1024, 0, 0, 0, nullptr);

  // ---- MoE (atomic-free routing)
  rmsnorm2_gate<<<T_, 256, 0, stream>>>(x1, ln2w, gate_w, xn, eidx, aw);
  route_scan<<<1, 256, 0, stream>>>(eidx, arow, cursor);
  gather_rows<<<4096, 256, 0, stream>>>(xn, arow, xg);
  gemm_bt<128, 1, 0, 1><<<dim3(16, 16, 8), 256, 0, stream>>>(
      xg, egu, hbuf, nullptr, 1024, 1024, 1024, MI_,
      (long)CAP_ * H_, (long)2 * MI_ * H_, (long)CAP_ * MI_, cursor);
  gemm_bt<128, 1, 0, 0><<<dim3(8, 16, 8), 256, 0, stream>>>(
      hbuf, edb, y, nullptr, 1024, 1024, 1024, 1024,
      (long)CAP_ * MI_, (long)H_ * MI_, (long)CAP_ * H_, cursor);
  // shared MLP
  gemm_bt<128, 1, 0, 1><<<dim3(32, 16, 1), 256, 0, stream>>>(
      xn, sgu, hs, nullptr, 1024, 1024, 1024, SI_, 0, 0, 0, nullptr);
  gemm_bt<64, 0, 0, 0><<<dim3(8, 32, 1), 256, 0, stream>>>(
      hs, sdb, ys, nullptr, 2048, 2048, 2048, 1024, 0, 0, 0, nullptr);

  final_combine<<<T_, 256, 0, stream>>>(x1, ys, y, arow, aw, out);
}

// Round 7
// 427.416 us; speedup vs baseline: 1.6161x; 1.1107x over previous
//
#include <hip/hip_runtime.h>

#define B_   2
#define S_   1024
#define H_   1024
#define NH_  8
#define HD_  128
#define E_   8
#define MI_  1024
#define SI_  2048
#define T_   2048
#define CAP_ 2048

typedef unsigned short u16;
typedef __attribute__((ext_vector_type(4))) float f32x4;
typedef __attribute__((ext_vector_type(4))) unsigned short u16x4;
typedef __attribute__((ext_vector_type(8))) __bf16 bf16x8;

__device__ __forceinline__ u16 f2bf(float f) {
  unsigned int u = __builtin_bit_cast(unsigned int, f);
  u = (u + 0x7fffu + ((u >> 16) & 1u)) >> 16;
  return (u16)u;
}
__device__ __forceinline__ float bf2f(u16 u) {
  return __builtin_bit_cast(float, (unsigned int)u << 16);
}
__device__ __forceinline__ float wave_sum(float v) {
#pragma unroll
  for (int o = 32; o; o >>= 1) v += __shfl_down(v, o, 64);
  return v;
}
// async global->LDS, 16B per lane, dest = wave-uniform base + lane*16
__device__ __forceinline__ void gll16(const u16* g, u16* l) {
  __builtin_amdgcn_global_load_lds((const __attribute__((address_space(1))) void*)g,
                                   (__attribute__((address_space(3))) void*)l, 16, 0, 0);
}

// ---------------- all weight conversions in ONE kernel
__global__ void cvt_all(const float* __restrict__ q_w, const float* __restrict__ k_w,
                        const float* __restrict__ v_w, const float* __restrict__ o_w,
                        const float* __restrict__ eg_w, const float* __restrict__ eu_w,
                        const float* __restrict__ ed_w, const float* __restrict__ sg_w,
                        const float* __restrict__ su_w, const float* __restrict__ sd_w,
                        u16* __restrict__ qwb, u16* __restrict__ egu, u16* __restrict__ edb,
                        u16* __restrict__ sgu, u16* __restrict__ sdb) {
  int bid = blockIdx.x, tid = threadIdx.x;
  const float* in;
  u16* outp;
  long f;
  if (bid < 4096) {                       // qkv+o: 4 x 1M contiguous
    f = ((long)bid * 256 + tid) * 4;
    int seg = (int)(f >> 20);
    in = (seg == 0) ? q_w : (seg == 1) ? k_w : (seg == 2) ? v_w : o_w;
    f32x4 v = *(const f32x4*)(in + (f & 1048575));
    u16x4 r;
#pragma unroll
    for (int c = 0; c < 4; c++) r[c] = f2bf(v[c]);
    *(u16x4*)(qwb + f) = r;
    return;
  } else if (bid < 20480) {               // expert g/u 16-row interleave
    int rel = bid - 4096;
    int zu = rel >= 8192;
    in = zu ? eu_w : eg_w;
    f = ((long)(rel & 8191) * 256 + tid) * 4;
    long e = f >> 20;
    long rem = f & 1048575;
    long i = rem >> 10, hh = rem & 1023;
    long orow = (i >> 4) * 32 + (i & 15) + (zu ? 16 : 0);
    outp = egu + (e * 2048 + orow) * 1024 + hh;
  } else if (bid < 28672) {               // ed plain 8M
    f = ((long)(bid - 20480) * 256 + tid) * 4;
    in = ed_w;
    outp = edb + f;
  } else if (bid < 32768) {               // shared g/u interleave (rows=2048)
    int rel = bid - 28672;
    int zu = rel >= 2048;
    in = zu ? su_w : sg_w;
    f = ((long)(rel & 2047) * 256 + tid) * 4;
    long i = f >> 10, hh = f & 1023;
    long orow = (i >> 4) * 32 + (i & 15) + (zu ? 16 : 0);
    outp = sgu + orow * 1024 + hh;
  } else {                                // sd plain 2M
    f = ((long)(bid - 32768) * 256 + tid) * 4;
    in = sd_w;
    outp = sdb + f;
  }
  f32x4 v = *(const f32x4*)(in + f);
  u16x4 r;
#pragma unroll
  for (int c = 0; c < 4; c++) r[c] = f2bf(v[c]);
  *(u16x4*)outp = r;
}

// ---------------- RMSNorm -> bf16
__global__ void rmsnorm_cvt(const float* __restrict__ x, const float* __restrict__ w,
                            u16* __restrict__ out) {
  int t = blockIdx.x, tid = threadIdx.x;
  f32x4 v = ((const f32x4*)(x + (long)t * H_))[tid];
  float ss = v[0]*v[0] + v[1]*v[1] + v[2]*v[2] + v[3]*v[3];
  __shared__ float red[4];
  float s = wave_sum(ss);
  if ((tid & 63) == 0) red[tid >> 6] = s;
  __syncthreads();
  float r = rsqrtf((red[0] + red[1] + red[2] + red[3]) * (1.0f / H_) + 1e-6f);
  f32x4 wv = ((const f32x4*)w)[tid];
  u16x4 o;
#pragma unroll
  for (int c = 0; c < 4; c++) o[c] = f2bf(v[c] * r * wv[c]);
  ((u16x4*)(out + (long)t * H_))[tid] = o;
}

// ---------------- fused RMSNorm2 + gate + top2 (no atomics)
__global__ void rmsnorm2_gate(const float* __restrict__ x1, const float* __restrict__ ln2w,
                              const float* __restrict__ gw, u16* __restrict__ xn,
                              int* __restrict__ eidx, float* __restrict__ aw) {
  int t = blockIdx.x, tid = threadIdx.x;
  int lane = tid & 63, wave = tid >> 6;
  f32x4 v = ((const f32x4*)(x1 + (long)t * H_))[tid];
  float ss = v[0]*v[0] + v[1]*v[1] + v[2]*v[2] + v[3]*v[3];
  __shared__ float redS[4];
  __shared__ float redE[4][E_];
  float s = wave_sum(ss);
  if (lane == 0) redS[wave] = s;
  __syncthreads();
  float r = rsqrtf((redS[0] + redS[1] + redS[2] + redS[3]) * (1.0f / H_) + 1e-6f);
  f32x4 wv = ((const f32x4*)ln2w)[tid];
  float xv[4];
  u16x4 o;
#pragma unroll
  for (int c = 0; c < 4; c++) { xv[c] = v[c] * r * wv[c]; o[c] = f2bf(xv[c]); }
  ((u16x4*)(xn + (long)t * H_))[tid] = o;
  float acc[E_];
#pragma unroll
  for (int e = 0; e < E_; e++) {
    f32x4 g = ((const f32x4*)(gw + (long)e * H_))[tid];
    acc[e] = xv[0]*g[0] + xv[1]*g[1] + xv[2]*g[2] + xv[3]*g[3];
  }
#pragma unroll
  for (int e = 0; e < E_; e++) acc[e] = wave_sum(acc[e]);
  if (lane == 0)
#pragma unroll
    for (int e = 0; e < E_; e++) redE[wave][e] = acc[e];
  __syncthreads();
  if (tid == 0) {
    float l[E_];
#pragma unroll
    for (int e = 0; e < E_; e++) l[e] = redE[0][e] + redE[1][e] + redE[2][e] + redE[3][e];
    float mx = l[0];
#pragma unroll
    for (int e = 1; e < E_; e++) mx = fmaxf(mx, l[e]);
    float p[E_], z = 0.f;
#pragma unroll
    for (int e = 0; e < E_; e++) { p[e] = __expf(l[e] - mx); z += p[e]; }
    int e0 = 0;
#pragma unroll
    for (int e = 1; e < E_; e++) if (p[e] > p[e0]) e0 = e;
    int e1 = (e0 == 0) ? 1 : 0;
#pragma unroll
    for (int e = 0; e < E_; e++) if (e != e0 && p[e] > p[e1]) e1 = e;
    float q0 = p[e0] / z, q1 = p[e1] / z;
    float invs = 1.0f / (q0 + q1 + 1e-20f);
    eidx[t * 2] = e0;
    eidx[t * 2 + 1] = e1;
    aw[t * 2] = q0 * invs;
    aw[t * 2 + 1] = q1 * invs;
  }
}

// ---------------- single-workgroup routing scan
__global__ __launch_bounds__(256) void route_scan(const int* __restrict__ eidx,
                                                  int* __restrict__ arow,
                                                  int* __restrict__ cursor) {
  __shared__ int sc[E_][256];
  int tid = threadIdx.x;
  unsigned c0 = 0, c1 = 0;
  int ebuf[16];
#pragma unroll
  for (int i = 0; i < 16; i++) {
    int e = eidx[tid * 16 + i];
    ebuf[i] = e;
    if (e < 4) c0 += 1u << (8 * e); else c1 += 1u << (8 * (e - 4));
  }
#pragma unroll
  for (int e = 0; e < E_; e++)
    sc[e][tid] = (e < 4) ? (int)((c0 >> (8 * e)) & 0xff) : (int)((c1 >> (8 * (e - 4))) & 0xff);
  __syncthreads();
  for (int st = 1; st < 256; st <<= 1) {
    int v[E_];
#pragma unroll
    for (int e = 0; e < E_; e++) v[e] = (tid >= st) ? sc[e][tid - st] : 0;
    __syncthreads();
#pragma unroll
    for (int e = 0; e < E_; e++) sc[e][tid] += v[e];
    __syncthreads();
  }
  if (tid == 255)
#pragma unroll
    for (int e = 0; e < E_; e++) cursor[e] = sc[e][255];
  int base[E_];
#pragma unroll
  for (int e = 0; e < E_; e++) {
    int own = (e < 4) ? (int)((c0 >> (8 * e)) & 0xff) : (int)((c1 >> (8 * (e - 4))) & 0xff);
    base[e] = sc[e][tid] - own;
  }
  __syncthreads();
#pragma unroll
  for (int e = 0; e < E_; e++) sc[e][tid] = base[e];
  __syncthreads();
  unsigned r0 = 0, r1 = 0;
#pragma unroll
  for (int i = 0; i < 16; i++) {
    int e = ebuf[i];
    int run = (e < 4) ? (int)((r0 >> (8 * e)) & 0xff) : (int)((r1 >> (8 * (e - 4))) & 0xff);
    arow[tid * 16 + i] = e * CAP_ + sc[e][tid] + run;
    if (e < 4) r0 += 1u << (8 * e); else r1 += 1u << (8 * (e - 4));
  }
}

// ---------------- RoPE + layout change (b,s,h,d)->(b,h,s,d), fp32->bf16; z picks q/k
__global__ void rope_cvt(const float* __restrict__ qf, const float* __restrict__ cs,
                         const float* __restrict__ sn, u16* __restrict__ qbb) {
  const float* q = qf + (long)blockIdx.z * 2097152;
  u16* qb = qbb + (long)blockIdx.z * 2097152;
  int rid = blockIdx.x * 2 + (threadIdx.x >> 7);
  int d = threadIdx.x & 127;
  int h = rid & (NH_ - 1);
  int bs = rid >> 3;
  int s = bs & (S_ - 1);
  int b = bs >> 10;
  long base = (long)rid * HD_;
  float v = q[base + d];
  float o = (d < 64) ? (-q[base + d + 64]) : q[base + d - 64];
  float res = v * cs[s * HD_ + d] + o * sn[s * HD_ + d];
  qb[((long)((b * NH_ + h) * S_ + s)) * HD_ + d] = f2bf(res);
}

// ---------------- V transpose: (b,s,h,d) fp32 -> (b,h,d,s) bf16
__global__ void vtrans(const float* __restrict__ v, u16* __restrict__ vt) {
  int bh = blockIdx.z, b = bh >> 3, h = bh & 7;
  int s0 = blockIdx.x * 32, d0 = blockIdx.y * 32;
  __shared__ u16 tile[32][33];
  for (int i = threadIdx.y; i < 32; i += 8) {
    float val = v[(((long)(b * S_ + s0 + i)) * NH_ + h) * HD_ + d0 + threadIdx.x];
    tile[i][threadIdx.x] = f2bf(val);
  }
  __syncthreads();
  for (int i = threadIdx.y; i < 32; i += 8) {
    vt[((long)bh * HD_ + d0 + i) * S_ + s0 + threadIdx.x] = tile[threadIdx.x][i];
  }
}

// ---------------- split-K flash attention partials (Po now bf16).
__global__ __launch_bounds__(256) void flash_part(
    const u16* __restrict__ qb, const u16* __restrict__ kb,
    const u16* __restrict__ vt, u16* __restrict__ Po,
    float* __restrict__ Pm, float* __restrict__ Pl) {
  int item = blockIdx.x;  // 0..39
  int bh = blockIdx.y;
  int qt, ch;
  if (item < 4)       { qt = item;                    ch = 0; }
  else if (item < 12) { qt = 4 + ((item - 4) >> 1);   ch = (item - 4) & 1; }
  else if (item < 24) { qt = 8 + (item - 12) / 3;     ch = (item - 12) % 3; }
  else                { qt = 12 + ((item - 24) >> 2); ch = (item - 24) & 3; }
  int j0 = ch * 4, j1 = min(j0 + 4, qt + 1);

  int tid = threadIdx.x;
  int wavei = tid >> 6, lane = tid & 63;
  int la = lane & 15, qd = lane >> 4;

  __shared__ __align__(16) u16 Ks[64 * 128];
  __shared__ __align__(16) u16 Vs[128 * 64];
  __shared__ __align__(16) u16 Ps[4][16 * 64];

  bf16x8 qf[4];
  const u16* qrow = qb + ((long)bh * S_ + qt * 64 + wavei * 16 + la) * HD_;
#pragma unroll
  for (int ks = 0; ks < 4; ks++)
    qf[ks] = *(const bf16x8*)(qrow + ks * 32 + qd * 8);

  f32x4 oacc[8];
#pragma unroll
  for (int nf = 0; nf < 8; nf++) oacc[nf] = (f32x4){0.f, 0.f, 0.f, 0.f};
  float m_i[4], l_i[4];
#pragma unroll
  for (int r = 0; r < 4; r++) { m_i[r] = -1e30f; l_i[r] = 0.f; }

  const u16* Kbase = kb + (long)bh * S_ * HD_;
  const u16* Vbase = vt + (long)bh * HD_ * S_;
  const float scale = 0.08838834764831845f;
  u16* pw = (u16*)Ps[wavei];
  int swz = la & 7;

  for (int j = j0; j < j1; j++) {
    __syncthreads();
#pragma unroll
    for (int t = 0; t < 4; t++) {
      int blk = t * 4 + wavei;
      int kr = blk * 4 + (lane >> 4);
      int kc = (lane & 15) ^ (kr & 7);
      gll16(Kbase + ((long)j * 64 + kr) * 128 + kc * 8, Ks + blk * 512);
      int vr = blk * 8 + (lane >> 3);
      int vc = (lane & 7) ^ (vr & 7);
      gll16(Vbase + (long)vr * 1024 + j * 64 + vc * 8, Vs + blk * 512);
    }
    __syncthreads();

    f32x4 sacc[4];
#pragma unroll
    for (int jf = 0; jf < 4; jf++) sacc[jf] = (f32x4){0.f, 0.f, 0.f, 0.f};
#pragma unroll
    for (int ks = 0; ks < 4; ks++)
#pragma unroll
      for (int jf = 0; jf < 4; jf++) {
        bf16x8 kfrag = *(const bf16x8*)(Ks + (jf * 16 + la) * 128 + ((ks * 4 + qd) ^ swz) * 8);
        sacc[jf] = __builtin_amdgcn_mfma_f32_16x16x32_bf16(qf[ks], kfrag, sacc[jf], 0, 0, 0);
      }

    float sv[4][4];
    int qglob = qt * 64 + wavei * 16 + qd * 4;
#pragma unroll
    for (int jf = 0; jf < 4; jf++) {
      int kglob = j * 64 + jf * 16 + la;
#pragma unroll
      for (int r = 0; r < 4; r++)
        sv[jf][r] = (kglob <= qglob + r) ? sacc[jf][r] * scale : -1e30f;
    }
    float mnew[4], alpha[4];
#pragma unroll
    for (int r = 0; r < 4; r++) {
      float mx = fmaxf(fmaxf(sv[0][r], sv[1][r]), fmaxf(sv[2][r], sv[3][r]));
#pragma unroll
      for (int o = 1; o < 16; o <<= 1) mx = fmaxf(mx, __shfl_xor(mx, o, 64));
      mnew[r] = fmaxf(m_i[r], mx);
      alpha[r] = __expf(m_i[r] - mnew[r]);
      m_i[r] = mnew[r];
    }
#pragma unroll
    for (int r = 0; r < 4; r++) {
      float sum = 0.f;
#pragma unroll
      for (int jf = 0; jf < 4; jf++) {
        float p = __expf(sv[jf][r] - mnew[r]);
        sv[jf][r] = p;
        sum += p;
      }
#pragma unroll
      for (int o = 1; o < 16; o <<= 1) sum += __shfl_xor(sum, o, 64);
      l_i[r] = l_i[r] * alpha[r] + sum;
    }
#pragma unroll
    for (int jf = 0; jf < 4; jf++)
#pragma unroll
      for (int r = 0; r < 4; r++) {
        int rp = qd * 4 + r;
        int e = jf * 16 + la;
        pw[rp * 64 + (((e >> 3) ^ (rp & 7)) << 3) + (e & 7)] = f2bf(sv[jf][r]);
      }
#pragma unroll
    for (int nf = 0; nf < 8; nf++)
#pragma unroll
      for (int r = 0; r < 4; r++) oacc[nf][r] *= alpha[r];
#pragma unroll
    for (int ks = 0; ks < 2; ks++) {
      bf16x8 pfrag = *(const bf16x8*)(pw + la * 64 + ((ks * 4 + qd) ^ swz) * 8);
#pragma unroll
      for (int nf = 0; nf < 8; nf++) {
        bf16x8 vfrag = *(const bf16x8*)(Vs + (nf * 16 + la) * 64 + (((ks * 4 + qd) & 7) ^ swz) * 8);
        oacc[nf] = __builtin_amdgcn_mfma_f32_16x16x32_bf16(pfrag, vfrag, oacc[nf], 0, 0, 0);
      }
    }
  }

  int pidx = (bh * 16 + qt) * 4 + ch;
  int rowb = wavei * 16 + qd * 4;
  u16* pob = Po + ((long)pidx * 64 + rowb) * 128;
#pragma unroll
  for (int r = 0; r < 4; r++)
#pragma unroll
    for (int nf = 0; nf < 8; nf++)
      pob[(long)r * 128 + nf * 16 + la] = f2bf(oacc[nf][r]);
  if (la == 0)
#pragma unroll
    for (int r = 0; r < 4; r++) {
      Pm[pidx * 64 + rowb + r] = m_i[r];
      Pl[pidx * 64 + rowb + r] = l_i[r];
    }
}

// ---------------- merge split-K partials -> attn (b,s,h*128+d) bf16
__global__ __launch_bounds__(256) void attn_merge(
    const u16* __restrict__ Po, const float* __restrict__ Pm,
    const float* __restrict__ Pl, u16* __restrict__ attn) {
  int qt = blockIdx.x, bh = blockIdx.y;
  int b = bh >> 3, h = bh & 7;
  int nch = (qt >> 2) + 1;
  int t = threadIdx.x;
  int row = t >> 2, cg = (t & 3) * 32;
  long base = (long)(bh * 16 + qt) * 4;
  float mv[4], wv[4];
  float M = -1e30f;
  for (int c = 0; c < nch; c++) { mv[c] = Pm[(base + c) * 64 + row]; M = fmaxf(M, mv[c]); }
  float L = 0.f;
  for (int c = 0; c < nch; c++) { wv[c] = __expf(mv[c] - M); L += wv[c] * Pl[(base + c) * 64 + row]; }
  float inv = 1.0f / L;
  f32x4 o[8];
#pragma unroll
  for (int k = 0; k < 8; k++) o[k] = (f32x4){0.f, 0.f, 0.f, 0.f};
  for (int c = 0; c < nch; c++) {
    const u16x4* src = (const u16x4*)(Po + ((base + c) * 64 + row) * 128 + cg);
#pragma unroll
    for (int k = 0; k < 8; k++) {
      u16x4 sv = src[k];
#pragma unroll
      for (int e = 0; e < 4; e++) o[k][e] += bf2f(sv[e]) * wv[c];
    }
  }
  u16* dst = attn + ((long)b * S_ + qt * 64 + row) * H_ + h * HD_ + cg;
#pragma unroll
  for (int k = 0; k < 8; k++) {
    u16x4 ov;
#pragma unroll
    for (int c = 0; c < 4; c++) ov[c] = f2bf(o[k][c] * inv);
    ((u16x4*)dst)[k] = ov;
  }
}

// ---------------- gather token rows into per-expert slabs
__global__ void gather_rows(const u16* __restrict__ xn, const int* __restrict__ arow,
                            u16* __restrict__ xg) {
  int a = blockIdx.x;
  int t = a >> 1;
  int row = arow[a];
  u16x4 v = ((const u16x4*)(xn + (long)t * H_))[threadIdx.x];
  ((u16x4*)(xg + (long)row * H_))[threadIdx.x] = v;
}

// ---------------- final: out = x1 + shared + w0*y[r0] + w1*y[r1]
__global__ void final_combine(const float* __restrict__ x1, const float* __restrict__ ys,
                              const u16* __restrict__ y, const int* __restrict__ arow,
                              const float* __restrict__ aw, float* __restrict__ out) {
  int t = blockIdx.x;
  int i = threadIdx.x * 4;
  int r0 = arow[t * 2], r1 = arow[t * 2 + 1];
  float w0 = aw[t * 2], w1 = aw[t * 2 + 1];
  f32x4 a = *(const f32x4*)(x1 + (long)t * H_ + i);
  f32x4 b = *(const f32x4*)(ys + (long)t * H_ + i);
  u16x4 y0 = *(const u16x4*)(y + (long)r0 * H_ + i);
  u16x4 y1 = *(const u16x4*)(y + (long)r1 * H_ + i);
  f32x4 o;
#pragma unroll
  for (int c = 0; c < 4; c++)
    o[c] = a[c] + b[c] + w0 * bf2f(y0[c]) + w1 * bf2f(y1[c]);
  *(f32x4*)(out + (long)t * H_ + i) = o;
}

// ---------------- bf16 MFMA GEMM. BK=64, XOR-swizzled LDS (16B chunk ^= row&7).
// C = A (MxK, k-contig) * B^T (NxK, k-contig). MT = 128 or 64.
template <int MT, int STORE_BF16, int ADD_RES, int FUSE_SILU>
__global__ __launch_bounds__(256) void gemm_bt(
    const u16* __restrict__ Ag, const u16* __restrict__ Bg, void* __restrict__ Cg,
    const float* __restrict__ Res, int K, int lda, int ldb, int ldc,
    long sAz, long sBz, long sCz, const int* __restrict__ mlimit) {
  constexpr int MR = MT / 32;
  int z = blockIdx.z;
  int m0 = blockIdx.y * MT, n0 = blockIdx.x * 128;
  if (mlimit && m0 >= mlimit[z]) return;
  const u16* A = Ag + z * sAz;
  const u16* B = Bg + z * sBz;
  long cbase = (long)z * sCz;

  __shared__ __align__(16) u16 As[MT * 64];
  __shared__ __align__(16) u16 Bs[128 * 64];
  int tid = threadIdx.x;
  int lane = tid & 63, wave = tid >> 6;
  int wm = (wave & 1) * (MT / 2), wn = (wave >> 1) * 64;
  int la = lane & 15, qd = lane >> 4;
  int sr = lane >> 3;                 // staging row within wave's 8-row group
  int scs = (lane & 7) ^ (sr & 7);    // swizzled source chunk

  const u16* ap[MT / 32];
  const u16* bp[4];
#pragma unroll
  for (int t = 0; t < MT / 32; t++)
    ap[t] = A + (long)(m0 + t * 32 + wave * 8 + sr) * lda + scs * 8;
#pragma unroll
  for (int t = 0; t < 4; t++)
    bp[t] = B + (long)(n0 + t * 32 + wave * 8 + sr) * ldb + scs * 8;

  f32x4 acc[MR][4];
#pragma unroll
  for (int i = 0; i < MR; i++)
#pragma unroll
    for (int j = 0; j < 4; j++) acc[i][j] = (f32x4){0.f, 0.f, 0.f, 0.f};

  int sw = la & 7;
  for (int k0 = 0; k0 < K; k0 += 64) {
    __syncthreads();
#pragma unroll
    for (int t = 0; t < MT / 32; t++)
      gll16(ap[t] + k0, As + (t * 32 + wave * 8) * 64);
#pragma unroll
    for (int t = 0; t < 4; t++)
      gll16(bp[t] + k0, Bs + (t * 32 + wave * 8) * 64);
    __syncthreads();
#pragma unroll
    for (int kk = 0; kk < 2; kk++) {
      bf16x8 af[MR], bf[4];
#pragma unroll
      for (int i = 0; i < MR; i++)
        af[i] = *(const bf16x8*)(As + (wm + i * 16 + la) * 64 + (((kk * 4 + qd) ^ sw) << 3));
#pragma unroll
      for (int j = 0; j < 4; j++)
        bf[j] = *(const bf16x8*)(Bs + (wn + j * 16 + la) * 64 + (((kk * 4 + qd) ^ sw) << 3));
#pragma unroll
      for (int i = 0; i < MR; i++)
#pragma unroll
        for (int j = 0; j < 4; j++)
          acc[i][j] = __builtin_amdgcn_mfma_f32_16x16x32_bf16(af[i], bf[j], acc[i][j], 0, 0, 0);
    }
  }

  if (FUSE_SILU) {
#pragma unroll
    for (int i = 0; i < MR; i++) {
#pragma unroll
      for (int jp = 0; jp < 2; jp++) {
        int hcol = ((n0 + wn) >> 1) + (jp << 4) + la;
#pragma unroll
        for (int r = 0; r < 4; r++) {
          int row = m0 + wm + i * 16 + qd * 4 + r;
          float g = acc[i][jp * 2][r], u = acc[i][jp * 2 + 1][r];
          float sg = g / (1.f + __expf(-g));
          ((u16*)Cg)[cbase + (long)row * ldc + hcol] = f2bf(sg * u);
        }
      }
    }
  } else {
#pragma unroll
    for (int i = 0; i < MR; i++) {
#pragma unroll
      for (int j = 0; j < 4; j++) {
        int col = n0 + wn + j * 16 + la;
#pragma unroll
        for (int r = 0; r < 4; r++) {
          int row = m0 + wm + i * 16 + qd * 4 + r;
          float v = acc[i][j][r];
          long ci = cbase + (long)row * ldc + col;
          if (ADD_RES) v += Res[(long)row * ldc + col];
          if (STORE_BF16) ((u16*)Cg)[ci] = f2bf(v);
          else ((float*)Cg)[ci] = v;
        }
      }
    }
  }
}

extern "C" void kernel_launch(void* const* d_in, const int* in_sizes, int n_in,
                              void* d_out, int out_size, void* d_ws, size_t ws_size,
                              hipStream_t stream) {
  const float* hidden = (const float*)d_in[0];
  const float* ln1w = (const float*)d_in[1];
  const float* ln2w = (const float*)d_in[2];
  const float* q_w = (const float*)d_in[3];
  const float* k_w = (const float*)d_in[4];
  const float* v_w = (const float*)d_in[5];
  const float* o_w = (const float*)d_in[6];
  const float* cosp = (const float*)d_in[7];
  const float* sinp = (const float*)d_in[8];
  const float* gate_w = (const float*)d_in[9];
  const float* eg_w = (const float*)d_in[10];
  const float* eu_w = (const float*)d_in[11];
  const float* ed_w = (const float*)d_in[12];
  const float* sg_w = (const float*)d_in[13];
  const float* su_w = (const float*)d_in[14];
  const float* sd_w = (const float*)d_in[15];
  float* out = (float*)d_out;

  char* w = (char*)d_ws;
  const size_t MB = 1u << 20;
  u16* qwb = (u16*)(w + 0 * MB);     // q,k,v,o bf16, 8MB
  u16* egu = (u16*)(w + 8 * MB);     // (E, 2*MI, H) interleaved g/u, 32MB
  u16* edb = (u16*)(w + 40 * MB);    // (E, H, MI) 16MB
  u16* sgu = (u16*)(w + 56 * MB);    // (2*SI, H) interleaved, 8MB
  u16* sdb = (u16*)(w + 64 * MB);    // (H, SI) 4MB
  float* x1 = (float*)(w + 68 * MB);
  u16* xn = (u16*)(w + 76 * MB);
  u16* attn = (u16*)(w + 80 * MB);
  int* cursor = (int*)(w + 84 * MB);
  int* arow = (int*)(w + 84 * MB + 1024);
  float* aw = (float*)(w + 84 * MB + 20 * 1024);
  int* eidx = (int*)(w + 84 * MB + 40 * 1024);
  // phase-1 arena
  float* qf = (float*)(w + 85 * MB);
  float* kf = (float*)(w + 93 * MB);
  float* vf = (float*)(w + 101 * MB);
  u16* qb = (u16*)(w + 109 * MB);
  u16* kb = (u16*)(w + 113 * MB);
  u16* vt = (u16*)(w + 117 * MB);
  u16* Po = (u16*)(w + 121 * MB);      // 1024 x 64 x 128 bf16 = 16.8MB
  float* Pm = (float*)(w + 155 * MB);  // 256KB
  float* Pl = (float*)(w + 156 * MB);  // 256KB
  // phase-2 arena (aliases phase-1)
  u16* xg = (u16*)(w + 85 * MB);     // (E,CAP,H) 32MB
  u16* hbuf = (u16*)(w + 121 * MB);  // (E,CAP,MI) 32MB
  u16* y = (u16*)(w + 157 * MB);     // (E,CAP,H) 32MB
  u16* hs = (u16*)(w + 189 * MB);    // (T,SI) 8MB
  float* ys = (float*)(w + 197 * MB);  // (T,H) 8MB

  const long M1 = 1048576, M2 = 2097152;

  // ---- all weight conversions, one launch
  cvt_all<<<34816, 256, 0, stream>>>(q_w, k_w, v_w, o_w, eg_w, eu_w, ed_w,
                                     sg_w, su_w, sd_w, qwb, egu, edb, sgu, sdb);

  // ---- attention
  rmsnorm_cvt<<<T_, 256, 0, stream>>>(hidden, ln1w, xn);
  gemm_bt<128, 0, 0, 0><<<dim3(8, 16, 3), 256, 0, stream>>>(
      xn, qwb, qf, nullptr, 1024, 1024, 1024, 1024, 0, M1, M2, nullptr);
  rope_cvt<<<dim3(8192, 1, 2), 256, 0, stream>>>(qf, cosp, sinp, qb);
  vtrans<<<dim3(32, 4, 16), dim3(32, 8), 0, stream>>>(vf, vt);
  flash_part<<<dim3(40, 16), 256, 0, stream>>>(qb, kb, vt, Po, Pm, Pl);
  attn_merge<<<dim3(16, 16), 256, 0, stream>>>(Po, Pm, Pl, attn);
  gemm_bt<64, 0, 1, 0><<<dim3(8, 32, 1), 256, 0, stream>>>(
      attn, qwb + 3 * M1, x1, hidden, 1024, 1024, 1024, 1024, 0, 0, 0, nullptr);

  // ---- MoE (atomic-free routing)
  rmsnorm2_gate<<<T_, 256, 0, stream>>>(x1, ln2w, gate_w, xn, eidx, aw);
  route_scan<<<1, 256, 0, stream>>>(eidx, arow, cursor);
  gather_rows<<<4096, 256, 0, stream>>>(xn, arow, xg);
  gemm_bt<128, 1, 0, 1><<<dim3(16, 16, 8), 256, 0, stream>>>(
      xg, egu, hbuf, nullptr, 1024, 1024, 1024, MI_,
      (long)CAP_ * H_, (long)2 * MI_ * H_, (long)CAP_ * MI_, cursor);
  gemm_bt<128, 1, 0, 0><<<dim3(8, 16, 8), 256, 0, stream>>>(
      hbuf, edb, y, nullptr, 1024, 1024, 1024, 1024,
      (long)CAP_ * MI_, (long)H_ * MI_, (long)CAP_ * H_, cursor);
  // shared MLP
  gemm_bt<128, 1, 0, 1><<<dim3(32, 16, 1), 256, 0, stream>>>(
      xn, sgu, hs, nullptr, 1024, 1024, 1024, SI_, 0, 0, 0, nullptr);
  gemm_bt<64, 0, 0, 0><<<dim3(8, 32, 1), 256, 0, stream>>>(
      hs, sdb, ys, nullptr, 2048, 2048, 2048, 1024, 0, 0, 0, nullptr);

  final_combine<<<T_, 256, 0, stream>>>(x1, ys, y, arow, aw, out);
}

// Round 8
// 422.464 us; speedup vs baseline: 1.6350x; 1.0117x over previous
//
#include <hip/hip_runtime.h>

#define B_   2
#define S_   1024
#define H_   1024
#define NH_  8
#define HD_  128
#define E_   8
#define MI_  1024
#define SI_  2048
#define T_   2048
#define CAP_ 2048

typedef unsigned short u16;
typedef __attribute__((ext_vector_type(4))) float f32x4;
typedef __attribute__((ext_vector_type(4))) unsigned short u16x4;
typedef __attribute__((ext_vector_type(8))) unsigned short u16x8;
typedef __attribute__((ext_vector_type(8))) __bf16 bf16x8;

__device__ __forceinline__ u16 f2bf(float f) {
  unsigned int u = __builtin_bit_cast(unsigned int, f);
  u = (u + 0x7fffu + ((u >> 16) & 1u)) >> 16;
  return (u16)u;
}
__device__ __forceinline__ float bf2f(u16 u) {
  return __builtin_bit_cast(float, (unsigned int)u << 16);
}
__device__ __forceinline__ float wave_sum(float v) {
#pragma unroll
  for (int o = 32; o; o >>= 1) v += __shfl_down(v, o, 64);
  return v;
}
// async global->LDS, 16B per lane, dest = wave-uniform base + lane*16
__device__ __forceinline__ void gll16(const u16* g, u16* l) {
  __builtin_amdgcn_global_load_lds((const __attribute__((address_space(1))) void*)g,
                                   (__attribute__((address_space(3))) void*)l, 16, 0, 0);
}

// ---------------- all weight conversions, 16 elems/thread (high MLP)
__global__ void cvt_all(const float* __restrict__ q_w, const float* __restrict__ k_w,
                        const float* __restrict__ v_w, const float* __restrict__ o_w,
                        const float* __restrict__ eg_w, const float* __restrict__ eu_w,
                        const float* __restrict__ ed_w, const float* __restrict__ sg_w,
                        const float* __restrict__ su_w, const float* __restrict__ sd_w,
                        u16* __restrict__ qwb, u16* __restrict__ egu, u16* __restrict__ edb,
                        u16* __restrict__ sgu, u16* __restrict__ sdb) {
  int bid = blockIdx.x, tid = threadIdx.x;
  const float* src;
  u16* dst;
  if (bid < 1024) {                        // qkv+o: 4 x 1M contiguous
    long f = (long)bid * 4096 + tid * 16;
    int seg = (int)(f >> 20);
    const float* in = (seg == 0) ? q_w : (seg == 1) ? k_w : (seg == 2) ? v_w : o_w;
    src = in + (f & 1048575);
    dst = qwb + f;
  } else if (bid < 5120) {                 // expert g/u 16-row interleave
    int rel = bid - 1024;
    int zu = rel >= 2048;
    long fl = (long)(rel & 2047) * 4096 + tid * 16;
    long e = fl >> 20;
    long rem = fl & 1048575;
    long i = rem >> 10, hh = rem & 1023;
    long orow = (i >> 4) * 32 + (i & 15) + (zu ? 16 : 0);
    src = (zu ? eu_w : eg_w) + fl;
    dst = egu + (e * 2048 + orow) * 1024 + hh;
  } else if (bid < 7168) {                 // ed plain 8M
    long fl = (long)(bid - 5120) * 4096 + tid * 16;
    src = ed_w + fl;
    dst = edb + fl;
  } else if (bid < 8192) {                 // shared g/u interleave
    int rel = bid - 7168;
    int zu = rel >= 512;
    long fl = (long)(rel & 511) * 4096 + tid * 16;
    long i = fl >> 10, hh = fl & 1023;
    long orow = (i >> 4) * 32 + (i & 15) + (zu ? 16 : 0);
    src = (zu ? su_w : sg_w) + fl;
    dst = sgu + orow * 1024 + hh;
  } else {                                 // sd plain 2M
    long fl = (long)(bid - 8192) * 4096 + tid * 16;
    src = sd_w + fl;
    dst = sdb + fl;
  }
  f32x4 v0 = ((const f32x4*)src)[0];
  f32x4 v1 = ((const f32x4*)src)[1];
  f32x4 v2 = ((const f32x4*)src)[2];
  f32x4 v3 = ((const f32x4*)src)[3];
  u16x8 r0, r1;
#pragma unroll
  for (int c = 0; c < 4; c++) {
    r0[c] = f2bf(v0[c]); r0[c + 4] = f2bf(v1[c]);
    r1[c] = f2bf(v2[c]); r1[c + 4] = f2bf(v3[c]);
  }
  ((u16x8*)dst)[0] = r0;
  ((u16x8*)dst)[1] = r1;
}

// ---------------- RMSNorm -> bf16
__global__ void rmsnorm_cvt(const float* __restrict__ x, const float* __restrict__ w,
                            u16* __restrict__ out) {
  int t = blockIdx.x, tid = threadIdx.x;
  f32x4 v = ((const f32x4*)(x + (long)t * H_))[tid];
  float ss = v[0]*v[0] + v[1]*v[1] + v[2]*v[2] + v[3]*v[3];
  __shared__ float red[4];
  float s = wave_sum(ss);
  if ((tid & 63) == 0) red[tid >> 6] = s;
  __syncthreads();
  float r = rsqrtf((red[0] + red[1] + red[2] + red[3]) * (1.0f / H_) + 1e-6f);
  f32x4 wv = ((const f32x4*)w)[tid];
  u16x4 o;
#pragma unroll
  for (int c = 0; c < 4; c++) o[c] = f2bf(v[c] * r * wv[c]);
  ((u16x4*)(out + (long)t * H_))[tid] = o;
}

// ---------------- fused RMSNorm2 + gate + top2 (no atomics)
__global__ void rmsnorm2_gate(const float* __restrict__ x1, const float* __restrict__ ln2w,
                              const float* __restrict__ gw, u16* __restrict__ xn,
                              int* __restrict__ eidx, float* __restrict__ aw) {
  int t = blockIdx.x, tid = threadIdx.x;
  int lane = tid & 63, wave = tid >> 6;
  f32x4 v = ((const f32x4*)(x1 + (long)t * H_))[tid];
  float ss = v[0]*v[0] + v[1]*v[1] + v[2]*v[2] + v[3]*v[3];
  __shared__ float redS[4];
  __shared__ float redE[4][E_];
  float s = wave_sum(ss);
  if (lane == 0) redS[wave] = s;
  __syncthreads();
  float r = rsqrtf((redS[0] + redS[1] + redS[2] + redS[3]) * (1.0f / H_) + 1e-6f);
  f32x4 wv = ((const f32x4*)ln2w)[tid];
  float xv[4];
  u16x4 o;
#pragma unroll
  for (int c = 0; c < 4; c++) { xv[c] = v[c] * r * wv[c]; o[c] = f2bf(xv[c]); }
  ((u16x4*)(xn + (long)t * H_))[tid] = o;
  float acc[E_];
#pragma unroll
  for (int e = 0; e < E_; e++) {
    f32x4 g = ((const f32x4*)(gw + (long)e * H_))[tid];
    acc[e] = xv[0]*g[0] + xv[1]*g[1] + xv[2]*g[2] + xv[3]*g[3];
  }
#pragma unroll
  for (int e = 0; e < E_; e++) acc[e] = wave_sum(acc[e]);
  if (lane == 0)
#pragma unroll
    for (int e = 0; e < E_; e++) redE[wave][e] = acc[e];
  __syncthreads();
  if (tid == 0) {
    float l[E_];
#pragma unroll
    for (int e = 0; e < E_; e++) l[e] = redE[0][e] + redE[1][e] + redE[2][e] + redE[3][e];
    float mx = l[0];
#pragma unroll
    for (int e = 1; e < E_; e++) mx = fmaxf(mx, l[e]);
    float p[E_], z = 0.f;
#pragma unroll
    for (int e = 0; e < E_; e++) { p[e] = __expf(l[e] - mx); z += p[e]; }
    int e0 = 0;
#pragma unroll
    for (int e = 1; e < E_; e++) if (p[e] > p[e0]) e0 = e;
    int e1 = (e0 == 0) ? 1 : 0;
#pragma unroll
    for (int e = 0; e < E_; e++) if (e != e0 && p[e] > p[e1]) e1 = e;
    float q0 = p[e0] / z, q1 = p[e1] / z;
    float invs = 1.0f / (q0 + q1 + 1e-20f);
    eidx[t * 2] = e0;
    eidx[t * 2 + 1] = e1;
    aw[t * 2] = q0 * invs;
    aw[t * 2 + 1] = q1 * invs;
  }
}

// ---------------- single-workgroup routing scan (also emits inverse map itok)
__global__ __launch_bounds__(256) void route_scan(const int* __restrict__ eidx,
                                                  int* __restrict__ arow,
                                                  int* __restrict__ cursor,
                                                  int* __restrict__ itok) {
  __shared__ int sc[E_][256];
  int tid = threadIdx.x;
  unsigned c0 = 0, c1 = 0;
  int ebuf[16];
#pragma unroll
  for (int i = 0; i < 16; i++) {
    int e = eidx[tid * 16 + i];
    ebuf[i] = e;
    if (e < 4) c0 += 1u << (8 * e); else c1 += 1u << (8 * (e - 4));
  }
#pragma unroll
  for (int e = 0; e < E_; e++)
    sc[e][tid] = (e < 4) ? (int)((c0 >> (8 * e)) & 0xff) : (int)((c1 >> (8 * (e - 4))) & 0xff);
  __syncthreads();
  for (int st = 1; st < 256; st <<= 1) {
    int v[E_];
#pragma unroll
    for (int e = 0; e < E_; e++) v[e] = (tid >= st) ? sc[e][tid - st] : 0;
    __syncthreads();
#pragma unroll
    for (int e = 0; e < E_; e++) sc[e][tid] += v[e];
    __syncthreads();
  }
  if (tid == 255)
#pragma unroll
    for (int e = 0; e < E_; e++) cursor[e] = sc[e][255];
  int base[E_];
#pragma unroll
  for (int e = 0; e < E_; e++) {
    int own = (e < 4) ? (int)((c0 >> (8 * e)) & 0xff) : (int)((c1 >> (8 * (e - 4))) & 0xff);
    base[e] = sc[e][tid] - own;
  }
  __syncthreads();
#pragma unroll
  for (int e = 0; e < E_; e++) sc[e][tid] = base[e];
  __syncthreads();
  unsigned r0 = 0, r1 = 0;
#pragma unroll
  for (int i = 0; i < 16; i++) {
    int e = ebuf[i];
    int run = (e < 4) ? (int)((r0 >> (8 * e)) & 0xff) : (int)((r1 >> (8 * (e - 4))) & 0xff);
    int row = e * CAP_ + sc[e][tid] + run;
    arow[tid * 16 + i] = row;
    itok[row] = (tid * 16 + i) >> 1;
    if (e < 4) r0 += 1u << (8 * e); else r1 += 1u << (8 * (e - 4));
  }
}

// ---------------- RoPE + layout change (b,s,h,d)->(b,h,s,d), bf16->bf16; z picks q/k
__global__ void rope_cvt(const u16* __restrict__ qf, const float* __restrict__ cs,
                         const float* __restrict__ sn, u16* __restrict__ qbb) {
  const u16* q = qf + (long)blockIdx.z * 2097152;
  u16* qb = qbb + (long)blockIdx.z * 2097152;
  int rid = blockIdx.x * 2 + (threadIdx.x >> 7);
  int d = threadIdx.x & 127;
  int h = rid & (NH_ - 1);
  int bs = rid >> 3;
  int s = bs & (S_ - 1);
  int b = bs >> 10;
  long base = (long)rid * HD_;
  float v = bf2f(q[base + d]);
  float o = (d < 64) ? (-bf2f(q[base + d + 64])) : bf2f(q[base + d - 64]);
  float res = v * cs[s * HD_ + d] + o * sn[s * HD_ + d];
  qb[((long)((b * NH_ + h) * S_ + s)) * HD_ + d] = f2bf(res);
}

// ---------------- V transpose: (b,s,h,d) bf16 -> (b,h,d,s) bf16
__global__ void vtrans(const u16* __restrict__ v, u16* __restrict__ vt) {
  int bh = blockIdx.z, b = bh >> 3, h = bh & 7;
  int s0 = blockIdx.x * 32, d0 = blockIdx.y * 32;
  __shared__ u16 tile[32][33];
  for (int i = threadIdx.y; i < 32; i += 8) {
    tile[i][threadIdx.x] = v[(((long)(b * S_ + s0 + i)) * NH_ + h) * HD_ + d0 + threadIdx.x];
  }
  __syncthreads();
  for (int i = threadIdx.y; i < 32; i += 8) {
    vt[((long)bh * HD_ + d0 + i) * S_ + s0 + threadIdx.x] = tile[threadIdx.x][i];
  }
}

// ---------------- split-K flash attention partials (Po bf16).
__global__ __launch_bounds__(256) void flash_part(
    const u16* __restrict__ qb, const u16* __restrict__ kb,
    const u16* __restrict__ vt, u16* __restrict__ Po,
    float* __restrict__ Pm, float* __restrict__ Pl) {
  int item = blockIdx.x;  // 0..39
  int bh = blockIdx.y;
  int qt, ch;
  if (item < 4)       { qt = item;                    ch = 0; }
  else if (item < 12) { qt = 4 + ((item - 4) >> 1);   ch = (item - 4) & 1; }
  else if (item < 24) { qt = 8 + (item - 12) / 3;     ch = (item - 12) % 3; }
  else                { qt = 12 + ((item - 24) >> 2); ch = (item - 24) & 3; }
  int j0 = ch * 4, j1 = min(j0 + 4, qt + 1);

  int tid = threadIdx.x;
  int wavei = tid >> 6, lane = tid & 63;
  int la = lane & 15, qd = lane >> 4;

  __shared__ __align__(16) u16 Ks[64 * 128];
  __shared__ __align__(16) u16 Vs[128 * 64];
  __shared__ __align__(16) u16 Ps[4][16 * 64];

  bf16x8 qf[4];
  const u16* qrow = qb + ((long)bh * S_ + qt * 64 + wavei * 16 + la) * HD_;
#pragma unroll
  for (int ks = 0; ks < 4; ks++)
    qf[ks] = *(const bf16x8*)(qrow + ks * 32 + qd * 8);

  f32x4 oacc[8];
#pragma unroll
  for (int nf = 0; nf < 8; nf++) oacc[nf] = (f32x4){0.f, 0.f, 0.f, 0.f};
  float m_i[4], l_i[4];
#pragma unroll
  for (int r = 0; r < 4; r++) { m_i[r] = -1e30f; l_i[r] = 0.f; }

  const u16* Kbase = kb + (long)bh * S_ * HD_;
  const u16* Vbase = vt + (long)bh * HD_ * S_;
  const float scale = 0.08838834764831845f;
  u16* pw = (u16*)Ps[wavei];
  int swz = la & 7;

  for (int j = j0; j < j1; j++) {
    __syncthreads();
#pragma unroll
    for (int t = 0; t < 4; t++) {
      int blk = t * 4 + wavei;
      int kr = blk * 4 + (lane >> 4);
      int kc = (lane & 15) ^ (kr & 7);
      gll16(Kbase + ((long)j * 64 + kr) * 128 + kc * 8, Ks + blk * 512);
      int vr = blk * 8 + (lane >> 3);
      int vc = (lane & 7) ^ (vr & 7);
      gll16(Vbase + (long)vr * 1024 + j * 64 + vc * 8, Vs + blk * 512);
    }
    __syncthreads();

    f32x4 sacc[4];
#pragma unroll
    for (int jf = 0; jf < 4; jf++) sacc[jf] = (f32x4){0.f, 0.f, 0.f, 0.f};
#pragma unroll
    for (int ks = 0; ks < 4; ks++)
#pragma unroll
      for (int jf = 0; jf < 4; jf++) {
        bf16x8 kfrag = *(const bf16x8*)(Ks + (jf * 16 + la) * 128 + ((ks * 4 + qd) ^ swz) * 8);
        sacc[jf] = __builtin_amdgcn_mfma_f32_16x16x32_bf16(qf[ks], kfrag, sacc[jf], 0, 0, 0);
      }

    float sv[4][4];
    int qglob = qt * 64 + wavei * 16 + qd * 4;
#pragma unroll
    for (int jf = 0; jf < 4; jf++) {
      int kglob = j * 64 + jf * 16 + la;
#pragma unroll
      for (int r = 0; r < 4; r++)
        sv[jf][r] = (kglob <= qglob + r) ? sacc[jf][r] * scale : -1e30f;
    }
    float mnew[4], alpha[4];
#pragma unroll
    for (int r = 0; r < 4; r++) {
      float mx = fmaxf(fmaxf(sv[0][r], sv[1][r]), fmaxf(sv[2][r], sv[3][r]));
#pragma unroll
      for (int o = 1; o < 16; o <<= 1) mx = fmaxf(mx, __shfl_xor(mx, o, 64));
      mnew[r] = fmaxf(m_i[r], mx);
      alpha[r] = __expf(m_i[r] - mnew[r]);
      m_i[r] = mnew[r];
    }
#pragma unroll
    for (int r = 0; r < 4; r++) {
      float sum = 0.f;
#pragma unroll
      for (int jf = 0; jf < 4; jf++) {
        float p = __expf(sv[jf][r] - mnew[r]);
        sv[jf][r] = p;
        sum += p;
      }
#pragma unroll
      for (int o = 1; o < 16; o <<= 1) sum += __shfl_xor(sum, o, 64);
      l_i[r] = l_i[r] * alpha[r] + sum;
    }
#pragma unroll
    for (int jf = 0; jf < 4; jf++)
#pragma unroll
      for (int r = 0; r < 4; r++) {
        int rp = qd * 4 + r;
        int e = jf * 16 + la;
        pw[rp * 64 + (((e >> 3) ^ (rp & 7)) << 3) + (e & 7)] = f2bf(sv[jf][r]);
      }
#pragma unroll
    for (int nf = 0; nf < 8; nf++)
#pragma unroll
      for (int r = 0; r < 4; r++) oacc[nf][r] *= alpha[r];
#pragma unroll
    for (int ks = 0; ks < 2; ks++) {
      bf16x8 pfrag = *(const bf16x8*)(pw + la * 64 + ((ks * 4 + qd) ^ swz) * 8);
#pragma unroll
      for (int nf = 0; nf < 8; nf++) {
        bf16x8 vfrag = *(const bf16x8*)(Vs + (nf * 16 + la) * 64 + (((ks * 4 + qd) & 7) ^ swz) * 8);
        oacc[nf] = __builtin_amdgcn_mfma_f32_16x16x32_bf16(pfrag, vfrag, oacc[nf], 0, 0, 0);
      }
    }
  }

  int pidx = (bh * 16 + qt) * 4 + ch;
  int rowb = wavei * 16 + qd * 4;
  u16* pob = Po + ((long)pidx * 64 + rowb) * 128;
#pragma unroll
  for (int r = 0; r < 4; r++)
#pragma unroll
    for (int nf = 0; nf < 8; nf++)
      pob[(long)r * 128 + nf * 16 + la] = f2bf(oacc[nf][r]);
  if (la == 0)
#pragma unroll
    for (int r = 0; r < 4; r++) {
      Pm[pidx * 64 + rowb + r] = m_i[r];
      Pl[pidx * 64 + rowb + r] = l_i[r];
    }
}

// ---------------- merge split-K partials -> attn (b,s,h*128+d) bf16
__global__ __launch_bounds__(256) void attn_merge(
    const u16* __restrict__ Po, const float* __restrict__ Pm,
    const float* __restrict__ Pl, u16* __restrict__ attn) {
  int qt = blockIdx.x, bh = blockIdx.y;
  int b = bh >> 3, h = bh & 7;
  int nch = (qt >> 2) + 1;
  int t = threadIdx.x;
  int row = t >> 2, cg = (t & 3) * 32;
  long base = (long)(bh * 16 + qt) * 4;
  float mv[4], wv[4];
  float M = -1e30f;
  for (int c = 0; c < nch; c++) { mv[c] = Pm[(base + c) * 64 + row]; M = fmaxf(M, mv[c]); }
  float L = 0.f;
  for (int c = 0; c < nch; c++) { wv[c] = __expf(mv[c] - M); L += wv[c] * Pl[(base + c) * 64 + row]; }
  float inv = 1.0f / L;
  f32x4 o[8];
#pragma unroll
  for (int k = 0; k < 8; k++) o[k] = (f32x4){0.f, 0.f, 0.f, 0.f};
  for (int c = 0; c < nch; c++) {
    const u16x4* src = (const u16x4*)(Po + ((base + c) * 64 + row) * 128 + cg);
#pragma unroll
    for (int k = 0; k < 8; k++) {
      u16x4 sv = src[k];
#pragma unroll
      for (int e = 0; e < 4; e++) o[k][e] += bf2f(sv[e]) * wv[c];
    }
  }
  u16* dst = attn + ((long)b * S_ + qt * 64 + row) * H_ + h * HD_ + cg;
#pragma unroll
  for (int k = 0; k < 8; k++) {
    u16x4 ov;
#pragma unroll
    for (int c = 0; c < 4; c++) ov[c] = f2bf(o[k][c] * inv);
    ((u16x4*)dst)[k] = ov;
  }
}

// ---------------- final: out = x1 + shared + w0*y[r0] + w1*y[r1]
__global__ void final_combine(const float* __restrict__ x1, const float* __restrict__ ys,
                              const u16* __restrict__ y, const int* __restrict__ arow,
                              const float* __restrict__ aw, float* __restrict__ out) {
  int t = blockIdx.x;
  int i = threadIdx.x * 4;
  int r0 = arow[t * 2], r1 = arow[t * 2 + 1];
  float w0 = aw[t * 2], w1 = aw[t * 2 + 1];
  f32x4 a = *(const f32x4*)(x1 + (long)t * H_ + i);
  f32x4 b = *(const f32x4*)(ys + (long)t * H_ + i);
  u16x4 y0 = *(const u16x4*)(y + (long)r0 * H_ + i);
  u16x4 y1 = *(const u16x4*)(y + (long)r1 * H_ + i);
  f32x4 o;
#pragma unroll
  for (int c = 0; c < 4; c++)
    o[c] = a[c] + b[c] + w0 * bf2f(y0[c]) + w1 * bf2f(y1[c]);
  *(f32x4*)(out + (long)t * H_ + i) = o;
}

// ---------------- bf16 MFMA GEMM. BK=64, XOR-swizzled LDS (16B chunk ^= row&7).
// C = A (MxK, k-contig) * B^T (NxK, k-contig). MT = 128 or 64.
// IND: A rows gathered via itok[z*CAP + row] (token indirection, xn as A base).
template <int MT, int STORE_BF16, int ADD_RES, int FUSE_SILU, int IND>
__global__ __launch_bounds__(256) void gemm_bt(
    const u16* __restrict__ Ag, const u16* __restrict__ Bg, void* __restrict__ Cg,
    const float* __restrict__ Res, int K, int lda, int ldb, int ldc,
    long sAz, long sBz, long sCz, const int* __restrict__ mlimit,
    const int* __restrict__ itok) {
  constexpr int MR = MT / 32;
  int z = blockIdx.z;
  int m0 = blockIdx.y * MT, n0 = blockIdx.x * 128;
  if (mlimit && m0 >= mlimit[z]) return;
  const u16* A = Ag + (IND ? 0 : z * sAz);
  const u16* B = Bg + z * sBz;
  long cbase = (long)z * sCz;

  __shared__ __align__(16) u16 As[MT * 64];
  __shared__ __align__(16) u16 Bs[128 * 64];
  int tid = threadIdx.x;
  int lane = tid & 63, wave = tid >> 6;
  int wm = (wave & 1) * (MT / 2), wn = (wave >> 1) * 64;
  int la = lane & 15, qd = lane >> 4;
  int sr = lane >> 3;                 // staging row within wave's 8-row group
  int scs = (lane & 7) ^ (sr & 7);    // swizzled source chunk

  const u16* ap[MT / 32];
  const u16* bp[4];
#pragma unroll
  for (int t = 0; t < MT / 32; t++) {
    int rloc = m0 + t * 32 + wave * 8 + sr;
    long arow_g = IND ? (long)itok[(long)z * CAP_ + rloc] : (long)rloc;
    ap[t] = A + arow_g * lda + scs * 8;
  }
#pragma unroll
  for (int t = 0; t < 4; t++)
    bp[t] = B + (long)(n0 + t * 32 + wave * 8 + sr) * ldb + scs * 8;

  f32x4 acc[MR][4];
#pragma unroll
  for (int i = 0; i < MR; i++)
#pragma unroll
    for (int j = 0; j < 4; j++) acc[i][j] = (f32x4){0.f, 0.f, 0.f, 0.f};

  int sw = la & 7;
  for (int k0 = 0; k0 < K; k0 += 64) {
    __syncthreads();
#pragma unroll
    for (int t = 0; t < MT / 32; t++)
      gll16(ap[t] + k0, As + (t * 32 + wave * 8) * 64);
#pragma unroll
    for (int t = 0; t < 4; t++)
      gll16(bp[t] + k0, Bs + (t * 32 + wave * 8) * 64);
    __syncthreads();
#pragma unroll
    for (int kk = 0; kk < 2; kk++) {
      bf16x8 af[MR], bf[4];
#pragma unroll
      for (int i = 0; i < MR; i++)
        af[i] = *(const bf16x8*)(As + (wm + i * 16 + la) * 64 + (((kk * 4 + qd) ^ sw) << 3));
#pragma unroll
      for (int j = 0; j < 4; j++)
        bf[j] = *(const bf16x8*)(Bs + (wn + j * 16 + la) * 64 + (((kk * 4 + qd) ^ sw) << 3));
#pragma unroll
      for (int i = 0; i < MR; i++)
#pragma unroll
        for (int j = 0; j < 4; j++)
          acc[i][j] = __builtin_amdgcn_mfma_f32_16x16x32_bf16(af[i], bf[j], acc[i][j], 0, 0, 0);
    }
  }

  if (FUSE_SILU) {
#pragma unroll
    for (int i = 0; i < MR; i++) {
#pragma unroll
      for (int jp = 0; jp < 2; jp++) {
        int hcol = ((n0 + wn) >> 1) + (jp << 4) + la;
#pragma unroll
        for (int r = 0; r < 4; r++) {
          int row = m0 + wm + i * 16 + qd * 4 + r;
          float g = acc[i][jp * 2][r], u = acc[i][jp * 2 + 1][r];
          float sg = g / (1.f + __expf(-g));
          ((u16*)Cg)[cbase + (long)row * ldc + hcol] = f2bf(sg * u);
        }
      }
    }
  } else {
#pragma unroll
    for (int i = 0; i < MR; i++) {
#pragma unroll
      for (int j = 0; j < 4; j++) {
        int col = n0 + wn + j * 16 + la;
#pragma unroll
        for (int r = 0; r < 4; r++) {
          int row = m0 + wm + i * 16 + qd * 4 + r;
          float v = acc[i][j][r];
          long ci = cbase + (long)row * ldc + col;
          if (ADD_RES) v += Res[(long)row * ldc + col];
          if (STORE_BF16) ((u16*)Cg)[ci] = f2bf(v);
          else ((float*)Cg)[ci] = v;
        }
      }
    }
  }
}

extern "C" void kernel_launch(void* const* d_in, const int* in_sizes, int n_in,
                              void* d_out, int out_size, void* d_ws, size_t ws_size,
                              hipStream_t stream) {
  const float* hidden = (const float*)d_in[0];
  const float* ln1w = (const float*)d_in[1];
  const float* ln2w = (const float*)d_in[2];
  const float* q_w = (const float*)d_in[3];
  const float* k_w = (const float*)d_in[4];
  const float* v_w = (const float*)d_in[5];
  const float* o_w = (const float*)d_in[6];
  const float* cosp = (const float*)d_in[7];
  const float* sinp = (const float*)d_in[8];
  const float* gate_w = (const float*)d_in[9];
  const float* eg_w = (const float*)d_in[10];
  const float* eu_w = (const float*)d_in[11];
  const float* ed_w = (const float*)d_in[12];
  const float* sg_w = (const float*)d_in[13];
  const float* su_w = (const float*)d_in[14];
  const float* sd_w = (const float*)d_in[15];
  float* out = (float*)d_out;

  char* w = (char*)d_ws;
  const size_t MB = 1u << 20;
  u16* qwb = (u16*)(w + 0 * MB);     // q,k,v,o bf16, 8MB
  u16* egu = (u16*)(w + 8 * MB);     // (E, 2*MI, H) interleaved g/u, 32MB
  u16* edb = (u16*)(w + 40 * MB);    // (E, H, MI) 16MB
  u16* sgu = (u16*)(w + 56 * MB);    // (2*SI, H) interleaved, 8MB
  u16* sdb = (u16*)(w + 64 * MB);    // (H, SI) 4MB
  float* x1 = (float*)(w + 68 * MB);
  u16* xn = (u16*)(w + 76 * MB);
  u16* attn = (u16*)(w + 80 * MB);
  int* cursor = (int*)(w + 84 * MB);
  int* arow = (int*)(w + 84 * MB + 1024);
  float* aw = (float*)(w + 84 * MB + 20 * 1024);
  int* eidx = (int*)(w + 84 * MB + 40 * 1024);
  int* itok = (int*)(w + 84 * MB + 60 * 1024);  // 64KB
  // phase-1 arena
  u16* qkvb = (u16*)(w + 85 * MB);   // (3, T, H) bf16, 12MB
  u16* qb = (u16*)(w + 109 * MB);
  u16* kb = (u16*)(w + 113 * MB);
  u16* vt = (u16*)(w + 117 * MB);
  u16* Po = (u16*)(w + 121 * MB);      // 1024 x 64 x 128 bf16 = 16.8MB
  float* Pm = (float*)(w + 155 * MB);  // 256KB
  float* Pl = (float*)(w + 156 * MB);  // 256KB
  // phase-2 arena (aliases phase-1)
  u16* hbuf = (u16*)(w + 121 * MB);  // (E,CAP,MI) 32MB
  u16* y = (u16*)(w + 157 * MB);     // (E,CAP,H) 32MB
  u16* hs = (u16*)(w + 189 * MB);    // (T,SI) 8MB
  float* ys = (float*)(w + 197 * MB);  // (T,H) 8MB

  const long M1 = 1048576, M2 = 2097152;

  // ---- all weight conversions, one launch (16 elems/thread)
  cvt_all<<<8704, 256, 0, stream>>>(q_w, k_w, v_w, o_w, eg_w, eu_w, ed_w,
                                    sg_w, su_w, sd_w, qwb, egu, edb, sgu, sdb);

  // ---- attention
  rmsnorm_cvt<<<T_, 256, 0, stream>>>(hidden, ln1w, xn);
  gemm_bt<128, 1, 0, 0, 0><<<dim3(8, 16, 3), 256, 0, stream>>>(
      xn, qwb, qkvb, nullptr, 1024, 1024, 1024, 1024, 0, M1, M2, nullptr, nullptr);
  rope_cvt<<<dim3(8192, 1, 2), 256, 0, stream>>>(qkvb, cosp, sinp, qb);
  vtrans<<<dim3(32, 4, 16), dim3(32, 8), 0, stream>>>(qkvb + 2 * M2, vt);
  flash_part<<<dim3(40, 16), 256, 0, stream>>>(qb, kb, vt, Po, Pm, Pl);
  attn_merge<<<dim3(16, 16), 256, 0, stream>>>(Po, Pm, Pl, attn);
  gemm_bt<64, 0, 1, 0, 0><<<dim3(8, 32, 1), 256, 0, stream>>>(
      attn, qwb + 3 * M1, x1, hidden, 1024, 1024, 1024, 1024, 0, 0, 0, nullptr, nullptr);

  // ---- MoE (atomic-free routing; indirect gather inside gu-GEMM)
  rmsnorm2_gate<<<T_, 256, 0, stream>>>(x1, ln2w, gate_w, xn, eidx, aw);
  hipMemsetAsync(itok, 0, E_ * CAP_ * 4, stream);
  route_scan<<<1, 256, 0, stream>>>(eidx, arow, cursor, itok);
  gemm_bt<128, 1, 0, 1, 1><<<dim3(16, 16, 8), 256, 0, stream>>>(
      xn, egu, hbuf, nullptr, 1024, 1024, 1024, MI_,
      0, (long)2 * MI_ * H_, (long)CAP_ * MI_, cursor, itok);
  gemm_bt<128, 1, 0, 0, 0><<<dim3(8, 16, 8), 256, 0, stream>>>(
      hbuf, edb, y, nullptr, 1024, 1024, 1024, 1024,
      (long)CAP_ * MI_, (long)H_ * MI_, (long)CAP_ * H_, cursor, nullptr);
  // shared MLP
  gemm_bt<128, 1, 0, 1, 0><<<dim3(32, 16, 1), 256, 0, stream>>>(
      xn, sgu, hs, nullptr, 1024, 1024, 1024, SI_, 0, 0, 0, nullptr, nullptr);
  gemm_bt<64, 0, 0, 0, 0><<<dim3(8, 32, 1), 256, 0, stream>>>(
      hs, sdb, ys, nullptr, 2048, 2048, 2048, 1024, 0, 0, 0, nullptr, nullptr);

  final_combine<<<T_, 256, 0, stream>>>(x1, ys, y, arow, aw, out);
}